// Round 4
// baseline (2445.577 us; speedup 1.0000x reference)
//
#include <hip/hip_runtime.h>
#include <hip/hip_bf16.h>

// ---------------------------------------------------------------------------
// NuGraphCore: 10 chained NuGraphBlocks.
// Block = sigmoid edge attention -> featurewise softmax aggregation -> MLP.
//
// r2 counters: edge_kernel atomic-bound. WRITE_SIZE == E*128*4B exactly =>
// every global f32 atomic is a memory-side HBM RMW; 208M ops @ ~296G/s
// ~= 700us of the 1533us total.
// r3: counting-sort edges by target bucket (W=2^k targets,
// W*128*4B <= 32KB LDS); one workgroup per bucket accumulates den/num via
// LDS atomics and writes its window with plain stores. Global f32 atomics
// eliminated; den/num memsets eliminated (buckets write full windows,
// empty target => den=0 => aggr=0 matching reference empty-segment).
// Sort: 3 kernels/launch (count, scan, scatter), all-static geometry.
// ---------------------------------------------------------------------------

typedef __bf16 bf16x8 __attribute__((ext_vector_type(8)));
typedef float  f32x4  __attribute__((ext_vector_type(4)));

__device__ __forceinline__ float b2f(ushort u) {
    return (float)__builtin_bit_cast(__bf16, u);
}
__device__ __forceinline__ ushort f2b(float f) {
    __bf16 h = (__bf16)f;
    return __builtin_bit_cast(ushort, h);
}
__device__ __forceinline__ __bf16 bhi(float x) { return (__bf16)x; }
__device__ __forceinline__ __bf16 blo(float x) {
    __bf16 h = (__bf16)x;
    return (__bf16)(x - (float)h);
}

// Dual-dtype loads: isb==1 -> bf16 (ushort), else fp32.
__device__ __forceinline__ float ldx(const void* p, long i, int isb) {
    return isb ? b2f(((const ushort*)p)[i]) : ((const float*)p)[i];
}
__device__ __forceinline__ f32x4 ldx4(const void* p, long i, int isb) {
    f32x4 r;
    if (isb) {
        uint2 v = *(const uint2*)((const ushort*)p + i);   // 8 B, aligned (i%4==0)
        r[0] = b2f((ushort)(v.x & 0xffff));
        r[1] = b2f((ushort)(v.x >> 16));
        r[2] = b2f((ushort)(v.y & 0xffff));
        r[3] = b2f((ushort)(v.y >> 16));
    } else {
        r = *(const f32x4*)((const float*)p + i);
    }
    return r;
}

__device__ __forceinline__ float frcp(float x) {
    return __builtin_amdgcn_rcpf(x);      // v_rcp_f32, ~1 ulp
}

__device__ __forceinline__ float mishf(float x) {
    // mish(x) = x * tanh(log1p(e^x)) = x * (1 - 2/((1+e^x)^2 + 1))
    float t = __expf(x);
    float u = 1.0f + t;
    float r = 1.0f - 2.0f * frcp(u * u + 1.0f);
    return x * r;
}

// ---------------------------------------------------------------------------
// Static graph geometry (all problem sizes are fixed).
// Block order: hit_sp, oph_pmt, pmt_opf, sp_evt, opf_evt, evt_sp, sp_hit,
//              evt_opf, opf_pmt, pmt_oph
// ---------------------------------------------------------------------------
#define NLIST 10
// E per list
#define E0 300000
#define E1 400000
#define E2 60000
#define E3 50000
#define E4 2000
#define E5 50000
#define E6 300000
#define E7 2000
#define E8 60000
#define E9 400000
#define ETOT 1624000
// bucket shift (W = 1<<SH targets/bucket; W*128*4B <= 32KB => SH<=6)
#define SH0 5
#define SH1 4
#define SH2 0
#define SH3 0
#define SH4 0
#define SH5 5
#define SH6 6
#define SH7 0
#define SH8 4
#define SH9 6
// bucket counts: ceil(n_tgt / W)
// {1563,1875,2000,256,256,1563,4688,2000,1875,3125}, total 19201
#define GB0 0
#define GB1 1563
#define GB2 3438
#define GB3 5438
#define GB4 5694
#define GB5 5950
#define GB6 7513
#define GB7 12201
#define GB8 14201
#define GB9 16076
#define NB_TOTAL 19201
#define NB_PAD   19456

// ---------------------------------------------------------------------------
// Dtype probe (unchanged): flag[0]=1 -> bf16 inputs, 0 -> fp32.
// ---------------------------------------------------------------------------
__global__ __launch_bounds__(256) void detect_kernel(const ushort* __restrict__ u,
                                                     int* __restrict__ flag)
{
    __shared__ int s_cnt;
    if (threadIdx.x == 0) s_cnt = 0;
    __syncthreads();
    int cnt = 0;
    for (int i = threadIdx.x; i < 8192; i += 256) {
        ushort v = u[2 * i];
        if ((v & 0x7F80u) == 0x7F80u) cnt++;
    }
#pragma unroll
    for (int off = 32; off; off >>= 1) cnt += __shfl_xor(cnt, off, 64);
    if ((threadIdx.x & 63) == 0) atomicAdd(&s_cnt, cnt);
    __syncthreads();
    if (threadIdx.x == 0) flag[0] = (s_cnt == 0) ? 1 : 0;
}

// ---------------------------------------------------------------------------
// Sort pass 1: count edges per bucket (int atomics; ~1.6M ops total).
// ---------------------------------------------------------------------------
__global__ __launch_bounds__(256) void count_kernel(
    const int* __restrict__ e0, const int* __restrict__ e1,
    const int* __restrict__ e2, const int* __restrict__ e3,
    const int* __restrict__ e4, const int* __restrict__ e5,
    const int* __restrict__ e6, const int* __restrict__ e7,
    const int* __restrict__ e8, const int* __restrict__ e9,
    int* __restrict__ cnt)
{
    long gid = (long)blockIdx.x * 256 + threadIdx.x;
    long gstride = (long)gridDim.x * 256;
#define CSEG(EP, EN, GB, SHV) \
    for (long i = gid; i < (EN); i += gstride) { \
        int d = (EP)[(EN) + i]; \
        atomicAdd(&cnt[(GB) + (d >> (SHV))], 1); \
    }
    CSEG(e0, E0, GB0, SH0) CSEG(e1, E1, GB1, SH1) CSEG(e2, E2, GB2, SH2)
    CSEG(e3, E3, GB3, SH3) CSEG(e4, E4, GB4, SH4) CSEG(e5, E5, GB5, SH5)
    CSEG(e6, E6, GB6, SH6) CSEG(e7, E7, GB7, SH7) CSEG(e8, E8, GB8, SH8)
    CSEG(e9, E9, GB9, SH9)
#undef CSEG
}

// ---------------------------------------------------------------------------
// Sort pass 2: exclusive scan of NB_TOTAL bucket counts (single workgroup).
// ---------------------------------------------------------------------------
__global__ __launch_bounds__(256) void scan_kernel(const int* __restrict__ cnt,
                                                   int* __restrict__ off)
{
    __shared__ int wsum[4];
    int tid = threadIdx.x;
    const int STRIP = (NB_TOTAL + 255) / 256;     // 76
    int s0 = tid * STRIP;
    int s1 = s0 + STRIP; if (s1 > NB_TOTAL) s1 = NB_TOTAL;
    int sum = 0;
    for (int i = s0; i < s1; ++i) sum += cnt[i];
    int lane = tid & 63, wid = tid >> 6;
    int incl = sum;
#pragma unroll
    for (int o = 1; o < 64; o <<= 1) {
        int v = __shfl_up(incl, o, 64);
        if (lane >= o) incl += v;
    }
    if (lane == 63) wsum[wid] = incl;
    __syncthreads();
    int wbase = 0;
    for (int wq = 0; wq < wid; ++wq) wbase += wsum[wq];
    int run = wbase + incl - sum;                 // exclusive prefix of strip
    for (int i = s0; i < s1; ++i) { off[i] = run; run += cnt[i]; }
}

// ---------------------------------------------------------------------------
// Sort pass 3: scatter (s,d) into bucket-contiguous order.
// After this, off[b] == end of bucket b (start = off[b-1] or 0).
// ---------------------------------------------------------------------------
__global__ __launch_bounds__(256) void scatter_kernel(
    const int* __restrict__ e0, const int* __restrict__ e1,
    const int* __restrict__ e2, const int* __restrict__ e3,
    const int* __restrict__ e4, const int* __restrict__ e5,
    const int* __restrict__ e6, const int* __restrict__ e7,
    const int* __restrict__ e8, const int* __restrict__ e9,
    int* __restrict__ off, int2* __restrict__ sdv)
{
    long gid = (long)blockIdx.x * 256 + threadIdx.x;
    long gstride = (long)gridDim.x * 256;
#define SSEG(EP, EN, GB, SHV) \
    for (long i = gid; i < (EN); i += gstride) { \
        int s = (EP)[i], d = (EP)[(EN) + i]; \
        int pos = atomicAdd(&off[(GB) + (d >> (SHV))], 1); \
        sdv[pos] = make_int2(s, d); \
    }
    SSEG(e0, E0, GB0, SH0) SSEG(e1, E1, GB1, SH1) SSEG(e2, E2, GB2, SH2)
    SSEG(e3, E3, GB3, SH3) SSEG(e4, E4, GB4, SH4) SSEG(e5, E5, GB5, SH5)
    SSEG(e6, E6, GB6, SH6) SSEG(e7, E7, GB7, SH7) SSEG(e8, E8, GB8, SH8)
    SSEG(e9, E9, GB9, SH9)
#undef SSEG
}

// ---------------------------------------------------------------------------
// Bucketed edge pass: one workgroup per bucket of W targets.
// LDS accumulation (ds atomics), plain coalesced global stores. No global
// f32 atomics. Also zero-fills windows of edgeless targets (=> aggr 0).
// ---------------------------------------------------------------------------
__global__ __launch_bounds__(256) void edge_bucket_kernel(
    const void* xsrc, long sOff, int smode,
    const void* xtgt, long tOff, int tmode,
    const int2* __restrict__ sdv, const int* __restrict__ boff,
    int gb0, int W, int lo, int hi,
    const void* ew, long ewOff, const void* eb, long ebOff,
    float* __restrict__ den, float* __restrict__ num,
    const int* __restrict__ flagp)
{
    __shared__ float acc[64 * 128];               // [row][den(64)|num(64)]

    int isb = flagp[0];
    int sm = (smode == 2) ? isb : smode;
    int tm = (tmode == 2) ? isb : tmode;

    int tid = threadIdx.x, lane = tid & 63, wid = tid >> 6;
    int t0 = lo + blockIdx.x * W;
    int rows = hi - t0; if (rows > W) rows = W;
    int gb = gb0 + blockIdx.x;
    int start = (gb == 0) ? 0 : boff[gb - 1];
    int end = boff[gb];

    for (int i = tid; i < rows * 128; i += 256) acc[i] = 0.0f;
    __syncthreads();

    float wI = ldx(ew, ewOff + lane, isb);
    float wJ = ldx(ew, ewOff + 64 + lane, isb);
    float bias = ldx(eb, ebOff, isb);

    for (int i = start + wid; i < end; i += 4) {  // wave per edge
        int2 e = sdv[i];
        float xj = ldx(xsrc, sOff + (long)e.x * 64 + lane, sm);
        float xi = ldx(xtgt, tOff + (long)e.y * 64 + lane, tm);
        float part = xi * wI + xj * wJ;
#pragma unroll
        for (int o = 32; o; o >>= 1) part += __shfl_xor(part, o, 64);
        float t = part + bias;
        float w = frcp(1.0f + __expf(-t));        // sigmoid
        float m = w * xj;
        float ex = __expf(m);
        int r = e.y - t0;
        atomicAdd(&acc[r * 128 + lane], ex);
        atomicAdd(&acc[r * 128 + 64 + lane], ex * m);
    }
    __syncthreads();

    for (int i = tid; i < rows * 16; i += 256) {
        int r = i >> 4, c = (i & 15) * 4;
        long go = (long)(t0 - lo + r) * 64 + c;
        *(f32x4*)&den[go] = *(const f32x4*)&acc[r * 128 + c];
        *(f32x4*)&num[go] = *(const f32x4*)&acc[r * 128 + 64 + c];
    }
}

// ---------------------------------------------------------------------------
// Fallback edge pass (global atomics) for small-workspace cases. Unchanged.
// ---------------------------------------------------------------------------
__global__ __launch_bounds__(256) void edge_kernel(
    const void* xsrc, long sOff, int smode,
    const void* xtgt, long tOff, int tmode,
    const int* __restrict__ eidx, int E,
    const void* ew, long ewOff, const void* eb, long ebOff,
    float* __restrict__ den, float* __restrict__ num,
    int lo, int hi, const int* __restrict__ flagp)
{
    int isb = flagp[0];
    int sm = (smode == 2) ? isb : smode;
    int tm = (tmode == 2) ? isb : tmode;

    int lane = threadIdx.x & 63;
    float wI = ldx(ew, ewOff + lane, isb);
    float wJ = ldx(ew, ewOff + 64 + lane, isb);
    float bias = ldx(eb, ebOff, isb);

    int nwaves = gridDim.x * 4;
    for (int e = blockIdx.x * 4 + (threadIdx.x >> 6); e < E; e += nwaves) {
        int d = eidx[E + e];
        if (d < lo || d >= hi) continue;
        int s = eidx[e];
        float xj = ldx(xsrc, sOff + (long)s * 64 + lane, sm);
        float xi = ldx(xtgt, tOff + (long)d * 64 + lane, tm);
        float part = xi * wI + xj * wJ;
#pragma unroll
        for (int off = 32; off; off >>= 1) part += __shfl_xor(part, off, 64);
        float t = part + bias;
        float w = frcp(1.0f + __expf(-t));
        float m = w * xj;
        float ex = __expf(m);
        long idx = (long)(d - lo) * 64 + lane;
        unsafeAtomicAdd(&den[idx], ex);
        unsafeAtomicAdd(&num[idx], ex * m);
    }
}

// ---------------------------------------------------------------------------
// MLP pass (unchanged from r2): aggr=num*rcp(den); 2-layer mish MLP via MFMA.
// ---------------------------------------------------------------------------
__global__ __launch_bounds__(256) void mlp_kernel(
    const float* __restrict__ den, const float* __restrict__ num,
    const void* xt, long xtOff, int tmode,
    const void* w1, long w1Off, const void* b1, long b1Off,
    const void* w2, long w2Off, const void* b2, long b2Off,
    float* outf, void* outd, long outOff,
    int lo, int hi, int accumulate, const int* __restrict__ flagp)
{
    __shared__ __align__(16) ushort W1t[64][144];
    __shared__ __align__(16) ushort W2t[64][80];
    __shared__ __align__(16) float  A2s[4][16][68];

    int isb = flagp[0];
    int tm = (tmode == 2) ? isb : tmode;
    ushort* ob16 = nullptr;
    float*  ob32 = nullptr;
    if (outd) {
        if (isb) ob16 = (ushort*)outd + outOff;
        else     ob32 = (float*)outd + outOff;
    }

    for (int idx = threadIdx.x; idx < 128 * 64; idx += 256) {
        int k = idx >> 6, n = idx & 63;
        W1t[n][k] = f2b(ldx(w1, w1Off + idx, isb));
    }
    for (int idx = threadIdx.x; idx < 64 * 64; idx += 256) {
        int k = idx >> 6, n = idx & 63;
        W2t[n][k] = f2b(ldx(w2, w2Off + idx, isb));
    }
    __syncthreads();

    int wid = threadIdx.x >> 6, lane = threadIdx.x & 63;
    int m16 = lane & 15, quad = lane >> 4;
    int ntiles = (hi - lo + 15) >> 4;

    for (int tile = blockIdx.x * 4 + wid; tile < ntiles; tile += gridDim.x * 4) {
        int base = lo + (tile << 4);
        int nodeA = base + m16;
        if (nodeA > hi - 1) nodeA = hi - 1;
        long aggoff = (long)(nodeA - lo) * 64;
        long xoff   = (long)nodeA * 64;

        bf16x8 Ahi[4], Alo[4];
#pragma unroll
        for (int s2 = 0; s2 < 2; ++s2) {
            int k0 = s2 * 32 + quad * 8;
            f32x4 n0v = *(const f32x4*)(num + aggoff + k0);
            f32x4 n1v = *(const f32x4*)(num + aggoff + k0 + 4);
            f32x4 d0v = *(const f32x4*)(den + aggoff + k0);
            f32x4 d1v = *(const f32x4*)(den + aggoff + k0 + 4);
#pragma unroll
            for (int j = 0; j < 4; ++j) {
                float a0 = n0v[j] * frcp(d0v[j] + 1e-16f);
                float a1 = n1v[j] * frcp(d1v[j] + 1e-16f);
                Ahi[s2][j]     = bhi(a0);
                Alo[s2][j]     = blo(a0);
                Ahi[s2][j + 4] = bhi(a1);
                Alo[s2][j + 4] = blo(a1);
            }
        }
#pragma unroll
        for (int s2 = 2; s2 < 4; ++s2) {
            int k0 = (s2 - 2) * 32 + quad * 8;
            f32x4 x0 = ldx4(xt, xtOff + xoff + k0, tm);
            f32x4 x1 = ldx4(xt, xtOff + xoff + k0 + 4, tm);
#pragma unroll
            for (int j = 0; j < 4; ++j) {
                Ahi[s2][j]     = bhi(x0[j]);
                Alo[s2][j]     = blo(x0[j]);
                Ahi[s2][j + 4] = bhi(x1[j]);
                Alo[s2][j + 4] = blo(x1[j]);
            }
        }

        f32x4 acc[4] = {};
#pragma unroll
        for (int t = 0; t < 4; ++t) {
#pragma unroll
            for (int s = 0; s < 4; ++s) {
                bf16x8 B = __builtin_bit_cast(bf16x8,
                    *(const int4*)&W1t[t * 16 + m16][s * 32 + quad * 8]);
                acc[t] = __builtin_amdgcn_mfma_f32_16x16x32_bf16(Ahi[s], B, acc[t], 0, 0, 0);
                acc[t] = __builtin_amdgcn_mfma_f32_16x16x32_bf16(Alo[s], B, acc[t], 0, 0, 0);
            }
        }
#pragma unroll
        for (int t = 0; t < 4; ++t) {
            float bias = ldx(b1, b1Off + t * 16 + m16, isb);
#pragma unroll
            for (int r = 0; r < 4; ++r) {
                float x = acc[t][r] + bias;
                A2s[wid][quad * 4 + r][t * 16 + m16] = mishf(x);
            }
        }
        asm volatile("s_waitcnt lgkmcnt(0)" ::: "memory");

        bf16x8 A2hi[2], A2lo[2];
#pragma unroll
        for (int s2 = 0; s2 < 2; ++s2) {
            int k0 = s2 * 32 + quad * 8;
            f32x4 h0 = *(const f32x4*)&A2s[wid][m16][k0];
            f32x4 h1 = *(const f32x4*)&A2s[wid][m16][k0 + 4];
#pragma unroll
            for (int j = 0; j < 4; ++j) {
                A2hi[s2][j]     = bhi(h0[j]);
                A2lo[s2][j]     = blo(h0[j]);
                A2hi[s2][j + 4] = bhi(h1[j]);
                A2lo[s2][j + 4] = blo(h1[j]);
            }
        }
        f32x4 acc2[4] = {};
#pragma unroll
        for (int t = 0; t < 4; ++t) {
#pragma unroll
            for (int s = 0; s < 2; ++s) {
                bf16x8 B = __builtin_bit_cast(bf16x8,
                    *(const int4*)&W2t[t * 16 + m16][s * 32 + quad * 8]);
                acc2[t] = __builtin_amdgcn_mfma_f32_16x16x32_bf16(A2hi[s], B, acc2[t], 0, 0, 0);
                acc2[t] = __builtin_amdgcn_mfma_f32_16x16x32_bf16(A2lo[s], B, acc2[t], 0, 0, 0);
            }
        }
#pragma unroll
        for (int t = 0; t < 4; ++t) {
            float bias = ldx(b2, b2Off + t * 16 + m16, isb);
#pragma unroll
            for (int r = 0; r < 4; ++r) {
                int node = base + quad * 4 + r;
                if (node < hi) {
                    long idx = (long)node * 64 + t * 16 + m16;
                    float y = mishf(acc2[t][r] + bias);
                    if (accumulate)
                        y += outf ? outf[idx] : (ob16 ? b2f(ob16[idx]) : ob32[idx]);
                    if (outf) outf[idx] = y;
                    if (ob16) ob16[idx] = f2b(y);
                    else if (ob32) ob32[idx] = y;
                }
            }
        }
    }
}

// ---------------------------------------------------------------------------
struct HBuf { const void* base; long off; int mode; };   // 0 f32, 1 bf16, 2 flag

// Sorted path: bucketed edge pass + mlp. No memsets needed.
static void run_block_sorted(HBuf src, HBuf tgt, int n_tgt, int bi,
                             int gbase, int shift,
                             const int2* sdv, const int* boff,
                             const void* edge_w, const void* edge_b,
                             const void* w1, const void* b1,
                             const void* w2, const void* b2,
                             float* den, float* num, int chunkCap,
                             float* outf, void* outd, long outOff, int accumulate,
                             const int* flagp, hipStream_t stream)
{
    int W = 1 << shift;
    for (int lo = 0; lo < n_tgt; lo += chunkCap) {
        int hi = lo + chunkCap < n_tgt ? lo + chunkCap : n_tgt;
        int nb = (hi - lo + W - 1) >> shift;
        edge_bucket_kernel<<<nb, 256, 0, stream>>>(
            src.base, src.off, src.mode, tgt.base, tgt.off, tgt.mode,
            sdv, boff, gbase + (lo >> shift), W, lo, hi,
            edge_w, (long)bi * 128, edge_b, (long)bi,
            den, num, flagp);
        int ntiles = (hi - lo + 15) / 16;
        int mblocks = (ntiles + 3) / 4;
        if (mblocks > 2048) mblocks = 2048;
        mlp_kernel<<<mblocks, 256, 0, stream>>>(
            den, num, tgt.base, tgt.off, tgt.mode,
            w1, (long)bi * 128 * 64, b1, (long)bi * 64,
            w2, (long)bi * 64 * 64, b2, (long)bi * 64,
            outf, outd, outOff, lo, hi, accumulate, flagp);
    }
}

// Fallback path (global atomics), as in r2.
static void run_block(HBuf src, HBuf tgt, const int* e, int E, int n_tgt, int bi,
                      const void* edge_w, const void* edge_b,
                      const void* w1, const void* b1,
                      const void* w2, const void* b2,
                      float* den, float* num, int chunkCap,
                      float* outf, void* outd, long outOff, int accumulate,
                      const int* flagp, hipStream_t stream)
{
    for (int lo = 0; lo < n_tgt; lo += chunkCap) {
        int hi = lo + chunkCap < n_tgt ? lo + chunkCap : n_tgt;
        size_t bytes = (size_t)(hi - lo) * 64 * 4;
        if (hi - lo == chunkCap) {
            (void)hipMemsetAsync(den, 0, 2 * bytes, stream);
        } else {
            (void)hipMemsetAsync(den, 0, bytes, stream);
            (void)hipMemsetAsync(num, 0, bytes, stream);
        }
        int eblocks = (E + 3) / 4;
        if (eblocks > 2048) eblocks = 2048;
        edge_kernel<<<eblocks, 256, 0, stream>>>(
            src.base, src.off, src.mode, tgt.base, tgt.off, tgt.mode,
            e, E, edge_w, (long)bi * 128, edge_b, (long)bi,
            den, num, lo, hi, flagp);
        int ntiles = (hi - lo + 15) / 16;
        int mblocks = (ntiles + 3) / 4;
        if (mblocks > 2048) mblocks = 2048;
        mlp_kernel<<<mblocks, 256, 0, stream>>>(
            den, num, tgt.base, tgt.off, tgt.mode,
            w1, (long)bi * 128 * 64, b1, (long)bi * 64,
            w2, (long)bi * 64 * 64, b2, (long)bi * 64,
            outf, outd, outOff, lo, hi, accumulate, flagp);
    }
}

extern "C" void kernel_launch(void* const* d_in, const int* in_sizes, int n_in,
                              void* d_out, int out_size, void* d_ws, size_t ws_size,
                              hipStream_t stream)
{
    (void)in_sizes; (void)n_in; (void)out_size;

    const void* x_hit = d_in[0];
    const void* x_sp  = d_in[1];
    const void* x_oph = d_in[2];
    const void* x_pmt = d_in[3];
    const void* x_opf = d_in[4];
    const void* x_evt = d_in[5];
    const void* edge_w = d_in[6];
    const void* edge_b = d_in[7];
    const void* w1 = d_in[8];
    const void* b1 = d_in[9];
    const void* w2 = d_in[10];
    const void* b2 = d_in[11];
    const int* e_hit_sp  = (const int*)d_in[12];
    const int* e_oph_pmt = (const int*)d_in[13];
    const int* e_pmt_opf = (const int*)d_in[14];
    const int* e_sp_evt  = (const int*)d_in[15];
    const int* e_opf_evt = (const int*)d_in[16];
    const int* e_evt_sp  = (const int*)d_in[17];
    const int* e_sp_hit  = (const int*)d_in[18];
    const int* e_evt_opf = (const int*)d_in[19];
    const int* e_opf_pmt = (const int*)d_in[20];
    const int* e_pmt_oph = (const int*)d_in[21];

    const long off_p = 0, off_n = 19200000, off_oph = 22400000,
               off_pmt = 35200000, off_opf = 37120000, off_i = 37248000;

    char* wsc = (char*)d_ws;
    int* flagp = (int*)(wsc + ((ws_size - 64) & ~(size_t)15));
    size_t usable = ws_size > 256 ? ws_size - 256 : 0;
    float* wsf = (float*)d_ws;

    detect_kernel<<<1, 256, 0, stream>>>((const ushort*)x_hit, flagp);

    const size_t nodeFloats = 3200000ull * 2 + 1920000ull * 2 + 128000ull * 2 + 16384ull;
    const size_t nodeBytes  = nodeFloats * 4;
    // Sorted-path buffers right after node buffers: sdv[ETOT] int2, cnt/off.
    const size_t sortFloats = (size_t)ETOT * 2 + 2 * NB_PAD;
    const size_t sortBytes  = sortFloats * 4;

    bool sortedPath = usable >= nodeBytes + sortBytes + (4ull << 20);
    bool fp32path   = usable >= nodeBytes + (8ull << 20);

    HBuf bhit{x_hit, 0, 2}, bsp{x_sp, 0, 2}, boph{x_oph, 0, 2},
         bpmt{x_pmt, 0, 2}, bopf{x_opf, 0, 2}, bevt{x_evt, 0, 2};

    if (sortedPath) {
        float* n0   = wsf;
        float* n1   = n0 + 3200000;
        float* pmt0 = n1 + 3200000;
        float* pmt1 = pmt0 + 1920000;
        float* opf0 = pmt1 + 1920000;
        float* opf1 = opf0 + 128000;
        float* iA   = opf1 + 128000;
        int2* sdv   = (int2*)(wsf + nodeFloats);
        int* cnt    = (int*)(sdv + ETOT);
        int* boff   = cnt + NB_PAD;
        float* den  = (float*)(boff + NB_PAD);

        size_t capBytes = usable - nodeBytes - sortBytes;
        long cap = (long)(capBytes / 512);
        if (cap > 300000) cap = 300000;
        cap &= ~63L;
        if (cap < 64) cap = 64;
        int chunkCap = (int)cap;
        float* num = den + (size_t)chunkCap * 64;

        // Build bucket-sorted edge lists (geometry all static).
        (void)hipMemsetAsync(cnt, 0, NB_PAD * sizeof(int), stream);
        count_kernel<<<512, 256, 0, stream>>>(
            e_hit_sp, e_oph_pmt, e_pmt_opf, e_sp_evt, e_opf_evt,
            e_evt_sp, e_sp_hit, e_evt_opf, e_opf_pmt, e_pmt_oph, cnt);
        scan_kernel<<<1, 256, 0, stream>>>(cnt, boff);
        scatter_kernel<<<512, 256, 0, stream>>>(
            e_hit_sp, e_oph_pmt, e_pmt_opf, e_sp_evt, e_opf_evt,
            e_evt_sp, e_sp_hit, e_evt_opf, e_opf_pmt, e_pmt_oph, boff, sdv);

        HBuf bn0{n0, 0, 0}, bn1{n1, 0, 0}, bpmt0{pmt0, 0, 0}, bpmt1{pmt1, 0, 0},
             bopf0{opf0, 0, 0}, bopf1{opf1, 0, 0}, biA{iA, 0, 0};

#define WS edge_w, edge_b, w1, b1, w2, b2, den, num, chunkCap
        run_block_sorted(bhit,  bsp,    50000, 0, GB0, SH0, sdv, boff, WS, n0,   nullptr, 0,      0, flagp, stream);
        run_block_sorted(boph,  bpmt,   30000, 1, GB1, SH1, sdv, boff, WS, pmt0, nullptr, 0,      0, flagp, stream);
        run_block_sorted(bpmt0, bopf,    2000, 2, GB2, SH2, sdv, boff, WS, opf0, nullptr, 0,      0, flagp, stream);
        run_block_sorted(bn0,   bevt,     256, 3, GB3, SH3, sdv, boff, WS, iA,   d_out, off_i,    0, flagp, stream);
        run_block_sorted(bopf0, bevt,     256, 4, GB4, SH4, sdv, boff, WS, iA,   d_out, off_i,    1, flagp, stream);
        run_block_sorted(biA,   bn0,    50000, 5, GB5, SH5, sdv, boff, WS, n1,   d_out, off_n,    0, flagp, stream);
        run_block_sorted(bn1,   bhit,  300000, 6, GB6, SH6, sdv, boff, WS, nullptr, d_out, off_p, 0, flagp, stream);
        run_block_sorted(biA,   bopf0,   2000, 7, GB7, SH7, sdv, boff, WS, opf1, d_out, off_opf,  0, flagp, stream);
        run_block_sorted(bopf1, bpmt0,  30000, 8, GB8, SH8, sdv, boff, WS, pmt1, d_out, off_pmt,  0, flagp, stream);
        run_block_sorted(bpmt1, boph,  200000, 9, GB9, SH9, sdv, boff, WS, nullptr, d_out, off_oph, 0, flagp, stream);
#undef WS
    } else if (fp32path) {
        size_t capBytes = usable - nodeBytes;
        long cap = (long)(capBytes / 512);
        if (cap > 300000) cap = 300000;
        cap &= ~15L;
        if (cap < 16) cap = 16;
        int chunkCap = (int)cap;
        float* den = wsf + nodeFloats;
        float* num = den + (size_t)chunkCap * 64;

        float* n0   = wsf;
        float* n1   = n0 + 3200000;
        float* pmt0 = n1 + 3200000;
        float* pmt1 = pmt0 + 1920000;
        float* opf0 = pmt1 + 1920000;
        float* opf1 = opf0 + 128000;
        float* iA   = opf1 + 128000;
        HBuf bn0{n0, 0, 0}, bn1{n1, 0, 0}, bpmt0{pmt0, 0, 0}, bpmt1{pmt1, 0, 0},
             bopf0{opf0, 0, 0}, bopf1{opf1, 0, 0}, biA{iA, 0, 0};

#define W edge_w, edge_b, w1, b1, w2, b2, den, num, chunkCap
        run_block(bhit,  bsp,   e_hit_sp,  300000,  50000, 0, W, n0,   nullptr, 0,      0, flagp, stream);
        run_block(boph,  bpmt,  e_oph_pmt, 400000,  30000, 1, W, pmt0, nullptr, 0,      0, flagp, stream);
        run_block(bpmt0, bopf,  e_pmt_opf,  60000,   2000, 2, W, opf0, nullptr, 0,      0, flagp, stream);
        run_block(bn0,   bevt,  e_sp_evt,   50000,    256, 3, W, iA,   d_out, off_i,    0, flagp, stream);
        run_block(bopf0, bevt,  e_opf_evt,   2000,    256, 4, W, iA,   d_out, off_i,    1, flagp, stream);
        run_block(biA,   bn0,   e_evt_sp,   50000,  50000, 5, W, n1,   d_out, off_n,    0, flagp, stream);
        run_block(bn1,   bhit,  e_sp_hit,  300000, 300000, 6, W, nullptr, d_out, off_p, 0, flagp, stream);
        run_block(biA,   bopf0, e_evt_opf,   2000,   2000, 7, W, opf1, d_out, off_opf,  0, flagp, stream);
        run_block(bopf1, bpmt0, e_opf_pmt,  60000,  30000, 8, W, pmt1, d_out, off_pmt,  0, flagp, stream);
        run_block(bpmt1, boph,  e_pmt_oph, 400000, 200000, 9, W, nullptr, d_out, off_oph, 0, flagp, stream);
#undef W
    } else {
        long cap = (long)(usable / 512);
        if (cap > 300000) cap = 300000;
        cap &= ~15L;
        if (cap < 16) cap = 16;
        int chunkCap = (int)cap;
        float* den = wsf;
        float* num = den + (size_t)chunkCap * 64;

        HBuf dn{d_out, off_n, 2}, dpmt{d_out, off_pmt, 2}, dopf{d_out, off_opf, 2},
             di{d_out, off_i, 2};
#define W edge_w, edge_b, w1, b1, w2, b2, den, num, chunkCap
        run_block(bhit, bsp,  e_hit_sp,  300000,  50000, 0, W, nullptr, d_out, off_n,   0, flagp, stream);
        run_block(boph, bpmt, e_oph_pmt, 400000,  30000, 1, W, nullptr, d_out, off_pmt, 0, flagp, stream);
        run_block(dpmt, bopf, e_pmt_opf,  60000,   2000, 2, W, nullptr, d_out, off_opf, 0, flagp, stream);
        run_block(dn,   bevt, e_sp_evt,   50000,    256, 3, W, nullptr, d_out, off_i,   0, flagp, stream);
        run_block(dopf, bevt, e_opf_evt,   2000,    256, 4, W, nullptr, d_out, off_i,   1, flagp, stream);
        run_block(di,   dn,   e_evt_sp,   50000,  50000, 5, W, nullptr, d_out, off_n,   0, flagp, stream);
        run_block(dn,   bhit, e_sp_hit,  300000, 300000, 6, W, nullptr, d_out, off_p,   0, flagp, stream);
        run_block(di,   dopf, e_evt_opf,   2000,   2000, 7, W, nullptr, d_out, off_opf, 0, flagp, stream);
        run_block(dopf, dpmt, e_opf_pmt,  60000,  30000, 8, W, nullptr, d_out, off_pmt, 0, flagp, stream);
        run_block(dpmt, boph, e_pmt_oph, 400000, 200000, 9, W, nullptr, d_out, off_oph, 0, flagp, stream);
#undef W
    }
}

// Round 5
// 2434.623 us; speedup vs baseline: 1.0045x; 1.0045x over previous
//
#include <hip/hip_runtime.h>
#include <hip/hip_bf16.h>

// ---------------------------------------------------------------------------
// NuGraphCore: 10 chained NuGraphBlocks.
// Block = sigmoid edge attention -> featurewise softmax aggregation -> MLP.
//
// r4 post-mortem: bucketed LDS edge pass eliminated atomics but was
// latency-starved: 32KB static LDS -> 3 blocks/CU, Occupancy 38%,
// VALUBusy 8%, HBM 6% -> 335us/400k-edge dispatch (vs 173 atomic-bound).
// r5: (1) template SHIFT, LDS sized exactly (1<<SH)*128 floats, W<=32
// => 16KB => 8 blocks/CU (32 waves/CU, launch_bounds(256,8));
// (2) software-pipeline the edge loop (prefetch next sdv + gathers before
// current reduce/exp/LDS-atomics) => 2 gather sets in flight per wave.
// Edges in flight per CU ~12 -> ~64.
// ---------------------------------------------------------------------------

typedef __bf16 bf16x8 __attribute__((ext_vector_type(8)));
typedef float  f32x4  __attribute__((ext_vector_type(4)));

__device__ __forceinline__ float b2f(ushort u) {
    return (float)__builtin_bit_cast(__bf16, u);
}
__device__ __forceinline__ ushort f2b(float f) {
    __bf16 h = (__bf16)f;
    return __builtin_bit_cast(ushort, h);
}
__device__ __forceinline__ __bf16 bhi(float x) { return (__bf16)x; }
__device__ __forceinline__ __bf16 blo(float x) {
    __bf16 h = (__bf16)x;
    return (__bf16)(x - (float)h);
}

// Dual-dtype loads: isb==1 -> bf16 (ushort), else fp32.
__device__ __forceinline__ float ldx(const void* p, long i, int isb) {
    return isb ? b2f(((const ushort*)p)[i]) : ((const float*)p)[i];
}
__device__ __forceinline__ f32x4 ldx4(const void* p, long i, int isb) {
    f32x4 r;
    if (isb) {
        uint2 v = *(const uint2*)((const ushort*)p + i);   // 8 B, aligned (i%4==0)
        r[0] = b2f((ushort)(v.x & 0xffff));
        r[1] = b2f((ushort)(v.x >> 16));
        r[2] = b2f((ushort)(v.y & 0xffff));
        r[3] = b2f((ushort)(v.y >> 16));
    } else {
        r = *(const f32x4*)((const float*)p + i);
    }
    return r;
}

__device__ __forceinline__ float frcp(float x) {
    return __builtin_amdgcn_rcpf(x);      // v_rcp_f32, ~1 ulp
}

__device__ __forceinline__ float mishf(float x) {
    // mish(x) = x * tanh(log1p(e^x)) = x * (1 - 2/((1+e^x)^2 + 1))
    float t = __expf(x);
    float u = 1.0f + t;
    float r = 1.0f - 2.0f * frcp(u * u + 1.0f);
    return x * r;
}

// ---------------------------------------------------------------------------
// Static graph geometry.
// Block order: hit_sp, oph_pmt, pmt_opf, sp_evt, opf_evt, evt_sp, sp_hit,
//              evt_opf, opf_pmt, pmt_oph
// ---------------------------------------------------------------------------
#define E0 300000
#define E1 400000
#define E2 60000
#define E3 50000
#define E4 2000
#define E5 50000
#define E6 300000
#define E7 2000
#define E8 60000
#define E9 400000
#define ETOT 1624000
// bucket shift (W = 1<<SH targets/bucket; W<=32 so LDS <= 16KB => 8 blk/CU)
#define SH0 5
#define SH1 4
#define SH2 0
#define SH3 0
#define SH4 0
#define SH5 5
#define SH6 5
#define SH7 0
#define SH8 4
#define SH9 5
// bucket counts: {1563,1875,2000,256,256,1563,9375,2000,1875,6250} sum 27013
#define GB0 0
#define GB1 1563
#define GB2 3438
#define GB3 5438
#define GB4 5694
#define GB5 5950
#define GB6 7513
#define GB7 16888
#define GB8 18888
#define GB9 20763
#define NB_TOTAL 27013
#define NB_PAD   27136

// ---------------------------------------------------------------------------
// Dtype probe: flag[0]=1 -> bf16 inputs, 0 -> fp32.
// ---------------------------------------------------------------------------
__global__ __launch_bounds__(256) void detect_kernel(const ushort* __restrict__ u,
                                                     int* __restrict__ flag)
{
    __shared__ int s_cnt;
    if (threadIdx.x == 0) s_cnt = 0;
    __syncthreads();
    int cnt = 0;
    for (int i = threadIdx.x; i < 8192; i += 256) {
        ushort v = u[2 * i];
        if ((v & 0x7F80u) == 0x7F80u) cnt++;
    }
#pragma unroll
    for (int off = 32; off; off >>= 1) cnt += __shfl_xor(cnt, off, 64);
    if ((threadIdx.x & 63) == 0) atomicAdd(&s_cnt, cnt);
    __syncthreads();
    if (threadIdx.x == 0) flag[0] = (s_cnt == 0) ? 1 : 0;
}

// ---------------------------------------------------------------------------
// Sort pass 1: count edges per bucket.
// ---------------------------------------------------------------------------
__global__ __launch_bounds__(256) void count_kernel(
    const int* __restrict__ e0, const int* __restrict__ e1,
    const int* __restrict__ e2, const int* __restrict__ e3,
    const int* __restrict__ e4, const int* __restrict__ e5,
    const int* __restrict__ e6, const int* __restrict__ e7,
    const int* __restrict__ e8, const int* __restrict__ e9,
    int* __restrict__ cnt)
{
    long gid = (long)blockIdx.x * 256 + threadIdx.x;
    long gstride = (long)gridDim.x * 256;
#define CSEG(EP, EN, GB, SHV) \
    for (long i = gid; i < (EN); i += gstride) { \
        int d = (EP)[(EN) + i]; \
        atomicAdd(&cnt[(GB) + (d >> (SHV))], 1); \
    }
    CSEG(e0, E0, GB0, SH0) CSEG(e1, E1, GB1, SH1) CSEG(e2, E2, GB2, SH2)
    CSEG(e3, E3, GB3, SH3) CSEG(e4, E4, GB4, SH4) CSEG(e5, E5, GB5, SH5)
    CSEG(e6, E6, GB6, SH6) CSEG(e7, E7, GB7, SH7) CSEG(e8, E8, GB8, SH8)
    CSEG(e9, E9, GB9, SH9)
#undef CSEG
}

// ---------------------------------------------------------------------------
// Sort pass 2: exclusive scan of NB_TOTAL bucket counts (single workgroup).
// ---------------------------------------------------------------------------
__global__ __launch_bounds__(256) void scan_kernel(const int* __restrict__ cnt,
                                                   int* __restrict__ off)
{
    __shared__ int wsum[4];
    int tid = threadIdx.x;
    const int STRIP = (NB_TOTAL + 255) / 256;     // 106
    int s0 = tid * STRIP;
    int s1 = s0 + STRIP; if (s1 > NB_TOTAL) s1 = NB_TOTAL;
    if (s0 > NB_TOTAL) s0 = NB_TOTAL;
    int sum = 0;
    for (int i = s0; i < s1; ++i) sum += cnt[i];
    int lane = tid & 63, wid = tid >> 6;
    int incl = sum;
#pragma unroll
    for (int o = 1; o < 64; o <<= 1) {
        int v = __shfl_up(incl, o, 64);
        if (lane >= o) incl += v;
    }
    if (lane == 63) wsum[wid] = incl;
    __syncthreads();
    int wbase = 0;
    for (int wq = 0; wq < wid; ++wq) wbase += wsum[wq];
    int run = wbase + incl - sum;                 // exclusive prefix of strip
    for (int i = s0; i < s1; ++i) { off[i] = run; run += cnt[i]; }
}

// ---------------------------------------------------------------------------
// Sort pass 3: scatter (s,d) into bucket-contiguous order.
// After this, off[b] == end of bucket b (start = off[b-1] or 0).
// ---------------------------------------------------------------------------
__global__ __launch_bounds__(256) void scatter_kernel(
    const int* __restrict__ e0, const int* __restrict__ e1,
    const int* __restrict__ e2, const int* __restrict__ e3,
    const int* __restrict__ e4, const int* __restrict__ e5,
    const int* __restrict__ e6, const int* __restrict__ e7,
    const int* __restrict__ e8, const int* __restrict__ e9,
    int* __restrict__ off, int2* __restrict__ sdv)
{
    long gid = (long)blockIdx.x * 256 + threadIdx.x;
    long gstride = (long)gridDim.x * 256;
#define SSEG(EP, EN, GB, SHV) \
    for (long i = gid; i < (EN); i += gstride) { \
        int s = (EP)[i], d = (EP)[(EN) + i]; \
        int pos = atomicAdd(&off[(GB) + (d >> (SHV))], 1); \
        sdv[pos] = make_int2(s, d); \
    }
    SSEG(e0, E0, GB0, SH0) SSEG(e1, E1, GB1, SH1) SSEG(e2, E2, GB2, SH2)
    SSEG(e3, E3, GB3, SH3) SSEG(e4, E4, GB4, SH4) SSEG(e5, E5, GB5, SH5)
    SSEG(e6, E6, GB6, SH6) SSEG(e7, E7, GB7, SH7) SSEG(e8, E8, GB8, SH8)
    SSEG(e9, E9, GB9, SH9)
#undef SSEG
}

// ---------------------------------------------------------------------------
// Bucketed edge pass: one workgroup per bucket of W=1<<SHIFT targets.
// LDS accumulation (ds atomics), software-pipelined gathers, plain stores.
// LDS sized exactly; W<=32 => 8 blocks/CU.
// ---------------------------------------------------------------------------
template <int SHIFT>
__global__ __launch_bounds__(256, 8) void edge_bucket_kernel(
    const void* xsrc, long sOff, int smode,
    const void* xtgt, long tOff, int tmode,
    const int2* __restrict__ sdv, const int* __restrict__ boff,
    int gb0, int lo, int hi,
    const void* ew, long ewOff, const void* eb, long ebOff,
    float* __restrict__ den, float* __restrict__ num,
    const int* __restrict__ flagp)
{
    constexpr int W = 1 << SHIFT;
    __shared__ float acc[W * 128];                // [row][den(64)|num(64)]

    int isb = flagp[0];
    int sm = (smode == 2) ? isb : smode;
    int tm = (tmode == 2) ? isb : tmode;

    int tid = threadIdx.x, lane = tid & 63, wid = tid >> 6;
    int t0 = lo + blockIdx.x * W;
    int rows = hi - t0; if (rows > W) rows = W;
    int gb = gb0 + blockIdx.x;
    int start = (gb == 0) ? 0 : boff[gb - 1];
    int end = boff[gb];

    for (int i = tid; i < rows * 128; i += 256) acc[i] = 0.0f;
    __syncthreads();

    float wI = ldx(ew, ewOff + lane, isb);
    float wJ = ldx(ew, ewOff + 64 + lane, isb);
    float bias = ldx(eb, ebOff, isb);

    // Software pipeline: keep next iteration's sdv + gathers in flight
    // while reducing/accumulating the current edge.
    int i = start + wid;
    int2 ecur = make_int2(0, t0);
    float xjc = 0.0f, xic = 0.0f;
    if (i < end) {
        ecur = sdv[i];
        xjc = ldx(xsrc, sOff + (long)ecur.x * 64 + lane, sm);
        xic = ldx(xtgt, tOff + (long)ecur.y * 64 + lane, tm);
    }
    while (i < end) {
        int inx = i + 4;
        int2 enx = make_int2(0, t0);
        float xjn = 0.0f, xin = 0.0f;
        if (inx < end) {
            enx = sdv[inx];
            xjn = ldx(xsrc, sOff + (long)enx.x * 64 + lane, sm);
            xin = ldx(xtgt, tOff + (long)enx.y * 64 + lane, tm);
        }
        float part = xic * wI + xjc * wJ;
#pragma unroll
        for (int o = 32; o; o >>= 1) part += __shfl_xor(part, o, 64);
        float t = part + bias;
        float w = frcp(1.0f + __expf(-t));        // sigmoid
        float m = w * xjc;
        float ex = __expf(m);
        int r = ecur.y - t0;
        atomicAdd(&acc[r * 128 + lane], ex);
        atomicAdd(&acc[r * 128 + 64 + lane], ex * m);
        i = inx; ecur = enx; xjc = xjn; xic = xin;
    }
    __syncthreads();

    for (int i2 = tid; i2 < rows * 16; i2 += 256) {
        int r = i2 >> 4, c = (i2 & 15) * 4;
        long go = (long)(t0 - lo + r) * 64 + c;
        *(f32x4*)&den[go] = *(const f32x4*)&acc[r * 128 + c];
        *(f32x4*)&num[go] = *(const f32x4*)&acc[r * 128 + 64 + c];
    }
}

// ---------------------------------------------------------------------------
// Fallback edge pass (global atomics) for small-workspace cases.
// ---------------------------------------------------------------------------
__global__ __launch_bounds__(256) void edge_kernel(
    const void* xsrc, long sOff, int smode,
    const void* xtgt, long tOff, int tmode,
    const int* __restrict__ eidx, int E,
    const void* ew, long ewOff, const void* eb, long ebOff,
    float* __restrict__ den, float* __restrict__ num,
    int lo, int hi, const int* __restrict__ flagp)
{
    int isb = flagp[0];
    int sm = (smode == 2) ? isb : smode;
    int tm = (tmode == 2) ? isb : tmode;

    int lane = threadIdx.x & 63;
    float wI = ldx(ew, ewOff + lane, isb);
    float wJ = ldx(ew, ewOff + 64 + lane, isb);
    float bias = ldx(eb, ebOff, isb);

    int nwaves = gridDim.x * 4;
    for (int e = blockIdx.x * 4 + (threadIdx.x >> 6); e < E; e += nwaves) {
        int d = eidx[E + e];
        if (d < lo || d >= hi) continue;
        int s = eidx[e];
        float xj = ldx(xsrc, sOff + (long)s * 64 + lane, sm);
        float xi = ldx(xtgt, tOff + (long)d * 64 + lane, tm);
        float part = xi * wI + xj * wJ;
#pragma unroll
        for (int off = 32; off; off >>= 1) part += __shfl_xor(part, off, 64);
        float t = part + bias;
        float w = frcp(1.0f + __expf(-t));
        float m = w * xj;
        float ex = __expf(m);
        long idx = (long)(d - lo) * 64 + lane;
        unsafeAtomicAdd(&den[idx], ex);
        unsafeAtomicAdd(&num[idx], ex * m);
    }
}

// ---------------------------------------------------------------------------
// MLP pass: aggr=num*rcp(den); 2-layer mish MLP via MFMA 16x16x32 bf16,
// hi/lo-split A for ~fp32 accuracy.
// ---------------------------------------------------------------------------
__global__ __launch_bounds__(256) void mlp_kernel(
    const float* __restrict__ den, const float* __restrict__ num,
    const void* xt, long xtOff, int tmode,
    const void* w1, long w1Off, const void* b1, long b1Off,
    const void* w2, long w2Off, const void* b2, long b2Off,
    float* outf, void* outd, long outOff,
    int lo, int hi, int accumulate, const int* __restrict__ flagp)
{
    __shared__ __align__(16) ushort W1t[64][144];
    __shared__ __align__(16) ushort W2t[64][80];
    __shared__ __align__(16) float  A2s[4][16][68];

    int isb = flagp[0];
    int tm = (tmode == 2) ? isb : tmode;
    ushort* ob16 = nullptr;
    float*  ob32 = nullptr;
    if (outd) {
        if (isb) ob16 = (ushort*)outd + outOff;
        else     ob32 = (float*)outd + outOff;
    }

    for (int idx = threadIdx.x; idx < 128 * 64; idx += 256) {
        int k = idx >> 6, n = idx & 63;
        W1t[n][k] = f2b(ldx(w1, w1Off + idx, isb));
    }
    for (int idx = threadIdx.x; idx < 64 * 64; idx += 256) {
        int k = idx >> 6, n = idx & 63;
        W2t[n][k] = f2b(ldx(w2, w2Off + idx, isb));
    }
    __syncthreads();

    int wid = threadIdx.x >> 6, lane = threadIdx.x & 63;
    int m16 = lane & 15, quad = lane >> 4;
    int ntiles = (hi - lo + 15) >> 4;

    for (int tile = blockIdx.x * 4 + wid; tile < ntiles; tile += gridDim.x * 4) {
        int base = lo + (tile << 4);
        int nodeA = base + m16;
        if (nodeA > hi - 1) nodeA = hi - 1;
        long aggoff = (long)(nodeA - lo) * 64;
        long xoff   = (long)nodeA * 64;

        bf16x8 Ahi[4], Alo[4];
#pragma unroll
        for (int s2 = 0; s2 < 2; ++s2) {
            int k0 = s2 * 32 + quad * 8;
            f32x4 n0v = *(const f32x4*)(num + aggoff + k0);
            f32x4 n1v = *(const f32x4*)(num + aggoff + k0 + 4);
            f32x4 d0v = *(const f32x4*)(den + aggoff + k0);
            f32x4 d1v = *(const f32x4*)(den + aggoff + k0 + 4);
#pragma unroll
            for (int j = 0; j < 4; ++j) {
                float a0 = n0v[j] * frcp(d0v[j] + 1e-16f);
                float a1 = n1v[j] * frcp(d1v[j] + 1e-16f);
                Ahi[s2][j]     = bhi(a0);
                Alo[s2][j]     = blo(a0);
                Ahi[s2][j + 4] = bhi(a1);
                Alo[s2][j + 4] = blo(a1);
            }
        }
#pragma unroll
        for (int s2 = 2; s2 < 4; ++s2) {
            int k0 = (s2 - 2) * 32 + quad * 8;
            f32x4 x0 = ldx4(xt, xtOff + xoff + k0, tm);
            f32x4 x1 = ldx4(xt, xtOff + xoff + k0 + 4, tm);
#pragma unroll
            for (int j = 0; j < 4; ++j) {
                Ahi[s2][j]     = bhi(x0[j]);
                Alo[s2][j]     = blo(x0[j]);
                Ahi[s2][j + 4] = bhi(x1[j]);
                Alo[s2][j + 4] = blo(x1[j]);
            }
        }

        f32x4 acc[4] = {};
#pragma unroll
        for (int t = 0; t < 4; ++t) {
#pragma unroll
            for (int s = 0; s < 4; ++s) {
                bf16x8 B = __builtin_bit_cast(bf16x8,
                    *(const int4*)&W1t[t * 16 + m16][s * 32 + quad * 8]);
                acc[t] = __builtin_amdgcn_mfma_f32_16x16x32_bf16(Ahi[s], B, acc[t], 0, 0, 0);
                acc[t] = __builtin_amdgcn_mfma_f32_16x16x32_bf16(Alo[s], B, acc[t], 0, 0, 0);
            }
        }
#pragma unroll
        for (int t = 0; t < 4; ++t) {
            float bias = ldx(b1, b1Off + t * 16 + m16, isb);
#pragma unroll
            for (int r = 0; r < 4; ++r) {
                float x = acc[t][r] + bias;
                A2s[wid][quad * 4 + r][t * 16 + m16] = mishf(x);
            }
        }
        asm volatile("s_waitcnt lgkmcnt(0)" ::: "memory");

        bf16x8 A2hi[2], A2lo[2];
#pragma unroll
        for (int s2 = 0; s2 < 2; ++s2) {
            int k0 = s2 * 32 + quad * 8;
            f32x4 h0 = *(const f32x4*)&A2s[wid][m16][k0];
            f32x4 h1 = *(const f32x4*)&A2s[wid][m16][k0 + 4];
#pragma unroll
            for (int j = 0; j < 4; ++j) {
                A2hi[s2][j]     = bhi(h0[j]);
                A2lo[s2][j]     = blo(h0[j]);
                A2hi[s2][j + 4] = bhi(h1[j]);
                A2lo[s2][j + 4] = blo(h1[j]);
            }
        }
        f32x4 acc2[4] = {};
#pragma unroll
        for (int t = 0; t < 4; ++t) {
#pragma unroll
            for (int s = 0; s < 2; ++s) {
                bf16x8 B = __builtin_bit_cast(bf16x8,
                    *(const int4*)&W2t[t * 16 + m16][s * 32 + quad * 8]);
                acc2[t] = __builtin_amdgcn_mfma_f32_16x16x32_bf16(A2hi[s], B, acc2[t], 0, 0, 0);
                acc2[t] = __builtin_amdgcn_mfma_f32_16x16x32_bf16(A2lo[s], B, acc2[t], 0, 0, 0);
            }
        }
#pragma unroll
        for (int t = 0; t < 4; ++t) {
            float bias = ldx(b2, b2Off + t * 16 + m16, isb);
#pragma unroll
            for (int r = 0; r < 4; ++r) {
                int node = base + quad * 4 + r;
                if (node < hi) {
                    long idx = (long)node * 64 + t * 16 + m16;
                    float y = mishf(acc2[t][r] + bias);
                    if (accumulate)
                        y += outf ? outf[idx] : (ob16 ? b2f(ob16[idx]) : ob32[idx]);
                    if (outf) outf[idx] = y;
                    if (ob16) ob16[idx] = f2b(y);
                    else if (ob32) ob32[idx] = y;
                }
            }
        }
    }
}

// ---------------------------------------------------------------------------
struct HBuf { const void* base; long off; int mode; };   // 0 f32, 1 bf16, 2 flag

// Sorted path: bucketed edge pass + mlp. No memsets needed.
template <int SHIFT>
static void run_block_sorted(HBuf src, HBuf tgt, int n_tgt, int bi, int gbase,
                             const int2* sdv, const int* boff,
                             const void* edge_w, const void* edge_b,
                             const void* w1, const void* b1,
                             const void* w2, const void* b2,
                             float* den, float* num, int chunkCap,
                             float* outf, void* outd, long outOff, int accumulate,
                             const int* flagp, hipStream_t stream)
{
    constexpr int W = 1 << SHIFT;
    for (int lo = 0; lo < n_tgt; lo += chunkCap) {
        int hi = lo + chunkCap < n_tgt ? lo + chunkCap : n_tgt;
        int nb = (hi - lo + W - 1) >> SHIFT;
        edge_bucket_kernel<SHIFT><<<nb, 256, 0, stream>>>(
            src.base, src.off, src.mode, tgt.base, tgt.off, tgt.mode,
            sdv, boff, gbase + (lo >> SHIFT), lo, hi,
            edge_w, (long)bi * 128, edge_b, (long)bi,
            den, num, flagp);
        int ntiles = (hi - lo + 15) / 16;
        int mblocks = (ntiles + 3) / 4;
        if (mblocks > 2048) mblocks = 2048;
        mlp_kernel<<<mblocks, 256, 0, stream>>>(
            den, num, tgt.base, tgt.off, tgt.mode,
            w1, (long)bi * 128 * 64, b1, (long)bi * 64,
            w2, (long)bi * 64 * 64, b2, (long)bi * 64,
            outf, outd, outOff, lo, hi, accumulate, flagp);
    }
}

// Fallback path (global atomics).
static void run_block(HBuf src, HBuf tgt, const int* e, int E, int n_tgt, int bi,
                      const void* edge_w, const void* edge_b,
                      const void* w1, const void* b1,
                      const void* w2, const void* b2,
                      float* den, float* num, int chunkCap,
                      float* outf, void* outd, long outOff, int accumulate,
                      const int* flagp, hipStream_t stream)
{
    for (int lo = 0; lo < n_tgt; lo += chunkCap) {
        int hi = lo + chunkCap < n_tgt ? lo + chunkCap : n_tgt;
        size_t bytes = (size_t)(hi - lo) * 64 * 4;
        if (hi - lo == chunkCap) {
            (void)hipMemsetAsync(den, 0, 2 * bytes, stream);
        } else {
            (void)hipMemsetAsync(den, 0, bytes, stream);
            (void)hipMemsetAsync(num, 0, bytes, stream);
        }
        int eblocks = (E + 3) / 4;
        if (eblocks > 2048) eblocks = 2048;
        edge_kernel<<<eblocks, 256, 0, stream>>>(
            src.base, src.off, src.mode, tgt.base, tgt.off, tgt.mode,
            e, E, edge_w, (long)bi * 128, edge_b, (long)bi,
            den, num, lo, hi, flagp);
        int ntiles = (hi - lo + 15) / 16;
        int mblocks = (ntiles + 3) / 4;
        if (mblocks > 2048) mblocks = 2048;
        mlp_kernel<<<mblocks, 256, 0, stream>>>(
            den, num, tgt.base, tgt.off, tgt.mode,
            w1, (long)bi * 128 * 64, b1, (long)bi * 64,
            w2, (long)bi * 64 * 64, b2, (long)bi * 64,
            outf, outd, outOff, lo, hi, accumulate, flagp);
    }
}

extern "C" void kernel_launch(void* const* d_in, const int* in_sizes, int n_in,
                              void* d_out, int out_size, void* d_ws, size_t ws_size,
                              hipStream_t stream)
{
    (void)in_sizes; (void)n_in; (void)out_size;

    const void* x_hit = d_in[0];
    const void* x_sp  = d_in[1];
    const void* x_oph = d_in[2];
    const void* x_pmt = d_in[3];
    const void* x_opf = d_in[4];
    const void* x_evt = d_in[5];
    const void* edge_w = d_in[6];
    const void* edge_b = d_in[7];
    const void* w1 = d_in[8];
    const void* b1 = d_in[9];
    const void* w2 = d_in[10];
    const void* b2 = d_in[11];
    const int* e_hit_sp  = (const int*)d_in[12];
    const int* e_oph_pmt = (const int*)d_in[13];
    const int* e_pmt_opf = (const int*)d_in[14];
    const int* e_sp_evt  = (const int*)d_in[15];
    const int* e_opf_evt = (const int*)d_in[16];
    const int* e_evt_sp  = (const int*)d_in[17];
    const int* e_sp_hit  = (const int*)d_in[18];
    const int* e_evt_opf = (const int*)d_in[19];
    const int* e_opf_pmt = (const int*)d_in[20];
    const int* e_pmt_oph = (const int*)d_in[21];

    const long off_p = 0, off_n = 19200000, off_oph = 22400000,
               off_pmt = 35200000, off_opf = 37120000, off_i = 37248000;

    char* wsc = (char*)d_ws;
    int* flagp = (int*)(wsc + ((ws_size - 64) & ~(size_t)15));
    size_t usable = ws_size > 256 ? ws_size - 256 : 0;
    float* wsf = (float*)d_ws;

    detect_kernel<<<1, 256, 0, stream>>>((const ushort*)x_hit, flagp);

    const size_t nodeFloats = 3200000ull * 2 + 1920000ull * 2 + 128000ull * 2 + 16384ull;
    const size_t nodeBytes  = nodeFloats * 4;
    const size_t sortFloats = (size_t)ETOT * 2 + 2 * NB_PAD;
    const size_t sortBytes  = sortFloats * 4;

    bool sortedPath = usable >= nodeBytes + sortBytes + (4ull << 20);
    bool fp32path   = usable >= nodeBytes + (8ull << 20);

    HBuf bhit{x_hit, 0, 2}, bsp{x_sp, 0, 2}, boph{x_oph, 0, 2},
         bpmt{x_pmt, 0, 2}, bopf{x_opf, 0, 2}, bevt{x_evt, 0, 2};

    if (sortedPath) {
        float* n0   = wsf;
        float* n1   = n0 + 3200000;
        float* pmt0 = n1 + 3200000;
        float* pmt1 = pmt0 + 1920000;
        float* opf0 = pmt1 + 1920000;
        float* opf1 = opf0 + 128000;
        float* iA   = opf1 + 128000;
        int2* sdv   = (int2*)(wsf + nodeFloats);
        int* cnt    = (int*)(sdv + ETOT);
        int* boff   = cnt + NB_PAD;
        float* den  = (float*)(boff + NB_PAD);

        size_t capBytes = usable - nodeBytes - sortBytes;
        long cap = (long)(capBytes / 512);
        if (cap > 300000) cap = 300000;
        cap &= ~63L;
        if (cap < 64) cap = 64;
        int chunkCap = (int)cap;
        float* num = den + (size_t)chunkCap * 64;

        // Build bucket-sorted edge lists (geometry all static).
        (void)hipMemsetAsync(cnt, 0, NB_PAD * sizeof(int), stream);
        count_kernel<<<512, 256, 0, stream>>>(
            e_hit_sp, e_oph_pmt, e_pmt_opf, e_sp_evt, e_opf_evt,
            e_evt_sp, e_sp_hit, e_evt_opf, e_opf_pmt, e_pmt_oph, cnt);
        scan_kernel<<<1, 256, 0, stream>>>(cnt, boff);
        scatter_kernel<<<512, 256, 0, stream>>>(
            e_hit_sp, e_oph_pmt, e_pmt_opf, e_sp_evt, e_opf_evt,
            e_evt_sp, e_sp_hit, e_evt_opf, e_opf_pmt, e_pmt_oph, boff, sdv);

        HBuf bn0{n0, 0, 0}, bn1{n1, 0, 0}, bpmt0{pmt0, 0, 0}, bpmt1{pmt1, 0, 0},
             bopf0{opf0, 0, 0}, bopf1{opf1, 0, 0}, biA{iA, 0, 0};

#define WS edge_w, edge_b, w1, b1, w2, b2, den, num, chunkCap
        run_block_sorted<SH0>(bhit,  bsp,    50000, 0, GB0, sdv, boff, WS, n0,   nullptr, 0,      0, flagp, stream);
        run_block_sorted<SH1>(boph,  bpmt,   30000, 1, GB1, sdv, boff, WS, pmt0, nullptr, 0,      0, flagp, stream);
        run_block_sorted<SH2>(bpmt0, bopf,    2000, 2, GB2, sdv, boff, WS, opf0, nullptr, 0,      0, flagp, stream);
        run_block_sorted<SH3>(bn0,   bevt,     256, 3, GB3, sdv, boff, WS, iA,   d_out, off_i,    0, flagp, stream);
        run_block_sorted<SH4>(bopf0, bevt,     256, 4, GB4, sdv, boff, WS, iA,   d_out, off_i,    1, flagp, stream);
        run_block_sorted<SH5>(biA,   bn0,    50000, 5, GB5, sdv, boff, WS, n1,   d_out, off_n,    0, flagp, stream);
        run_block_sorted<SH6>(bn1,   bhit,  300000, 6, GB6, sdv, boff, WS, nullptr, d_out, off_p, 0, flagp, stream);
        run_block_sorted<SH7>(biA,   bopf0,   2000, 7, GB7, sdv, boff, WS, opf1, d_out, off_opf,  0, flagp, stream);
        run_block_sorted<SH8>(bopf1, bpmt0,  30000, 8, GB8, sdv, boff, WS, pmt1, d_out, off_pmt,  0, flagp, stream);
        run_block_sorted<SH9>(bpmt1, boph,  200000, 9, GB9, sdv, boff, WS, nullptr, d_out, off_oph, 0, flagp, stream);
#undef WS
    } else if (fp32path) {
        size_t capBytes = usable - nodeBytes;
        long cap = (long)(capBytes / 512);
        if (cap > 300000) cap = 300000;
        cap &= ~15L;
        if (cap < 16) cap = 16;
        int chunkCap = (int)cap;
        float* den = wsf + nodeFloats;
        float* num = den + (size_t)chunkCap * 64;

        float* n0   = wsf;
        float* n1   = n0 + 3200000;
        float* pmt0 = n1 + 3200000;
        float* pmt1 = pmt0 + 1920000;
        float* opf0 = pmt1 + 1920000;
        float* opf1 = opf0 + 128000;
        float* iA   = opf1 + 128000;
        HBuf bn0{n0, 0, 0}, bn1{n1, 0, 0}, bpmt0{pmt0, 0, 0}, bpmt1{pmt1, 0, 0},
             bopf0{opf0, 0, 0}, bopf1{opf1, 0, 0}, biA{iA, 0, 0};

#define W edge_w, edge_b, w1, b1, w2, b2, den, num, chunkCap
        run_block(bhit,  bsp,   e_hit_sp,  300000,  50000, 0, W, n0,   nullptr, 0,      0, flagp, stream);
        run_block(boph,  bpmt,  e_oph_pmt, 400000,  30000, 1, W, pmt0, nullptr, 0,      0, flagp, stream);
        run_block(bpmt0, bopf,  e_pmt_opf,  60000,   2000, 2, W, opf0, nullptr, 0,      0, flagp, stream);
        run_block(bn0,   bevt,  e_sp_evt,   50000,    256, 3, W, iA,   d_out, off_i,    0, flagp, stream);
        run_block(bopf0, bevt,  e_opf_evt,   2000,    256, 4, W, iA,   d_out, off_i,    1, flagp, stream);
        run_block(biA,   bn0,   e_evt_sp,   50000,  50000, 5, W, n1,   d_out, off_n,    0, flagp, stream);
        run_block(bn1,   bhit,  e_sp_hit,  300000, 300000, 6, W, nullptr, d_out, off_p, 0, flagp, stream);
        run_block(biA,   bopf0, e_evt_opf,   2000,   2000, 7, W, opf1, d_out, off_opf,  0, flagp, stream);
        run_block(bopf1, bpmt0, e_opf_pmt,  60000,  30000, 8, W, pmt1, d_out, off_pmt,  0, flagp, stream);
        run_block(bpmt1, boph,  e_pmt_oph, 400000, 200000, 9, W, nullptr, d_out, off_oph, 0, flagp, stream);
#undef W
    } else {
        long cap = (long)(usable / 512);
        if (cap > 300000) cap = 300000;
        cap &= ~15L;
        if (cap < 16) cap = 16;
        int chunkCap = (int)cap;
        float* den = wsf;
        float* num = den + (size_t)chunkCap * 64;

        HBuf dn{d_out, off_n, 2}, dpmt{d_out, off_pmt, 2}, dopf{d_out, off_opf, 2},
             di{d_out, off_i, 2};
#define W edge_w, edge_b, w1, b1, w2, b2, den, num, chunkCap
        run_block(bhit, bsp,  e_hit_sp,  300000,  50000, 0, W, nullptr, d_out, off_n,   0, flagp, stream);
        run_block(boph, bpmt, e_oph_pmt, 400000,  30000, 1, W, nullptr, d_out, off_pmt, 0, flagp, stream);
        run_block(dpmt, bopf, e_pmt_opf,  60000,   2000, 2, W, nullptr, d_out, off_opf, 0, flagp, stream);
        run_block(dn,   bevt, e_sp_evt,   50000,    256, 3, W, nullptr, d_out, off_i,   0, flagp, stream);
        run_block(dopf, bevt, e_opf_evt,   2000,    256, 4, W, nullptr, d_out, off_i,   1, flagp, stream);
        run_block(di,   dn,   e_evt_sp,   50000,  50000, 5, W, nullptr, d_out, off_n,   0, flagp, stream);
        run_block(dn,   bhit, e_sp_hit,  300000, 300000, 6, W, nullptr, d_out, off_p,   0, flagp, stream);
        run_block(di,   dopf, e_evt_opf,   2000,   2000, 7, W, nullptr, d_out, off_opf, 0, flagp, stream);
        run_block(dopf, dpmt, e_opf_pmt,  60000,  30000, 8, W, nullptr, d_out, off_pmt, 0, flagp, stream);
        run_block(dpmt, boph, e_pmt_oph, 400000, 200000, 9, W, nullptr, d_out, off_oph, 0, flagp, stream);
#undef W
    }
}

// Round 6
// 2336.846 us; speedup vs baseline: 1.0465x; 1.0418x over previous
//
#include <hip/hip_runtime.h>
#include <hip/hip_bf16.h>

// ---------------------------------------------------------------------------
// NuGraphCore: 10 chained NuGraphBlocks.
// Block = sigmoid edge attention -> featurewise softmax aggregation -> MLP.
//
// r5 post-mortem: bucket edge pass is per-wave LATENCY-bound, not occupancy
// bound (occ 38->59% changed nothing; ~15k stall cycles per edge iteration;
// one edge retired per serial chain sdv->gather->6-shfl-reduce->exp).
// r6: 4 edges per wave. Lane layout: g=lane>>4 (edge slot), fl=(lane&15)*4
// (float4 feature base). One dwordx4 gather instruction covers 4 edges'
// 256B rows; reduce is 4 shfl levels within 16-lane groups; per-edge
// latency cost /4, in-flight bytes per wave x4. Sort/MLP/host unchanged.
// ---------------------------------------------------------------------------

typedef __bf16 bf16x8 __attribute__((ext_vector_type(8)));
typedef float  f32x4  __attribute__((ext_vector_type(4)));

__device__ __forceinline__ float b2f(ushort u) {
    return (float)__builtin_bit_cast(__bf16, u);
}
__device__ __forceinline__ ushort f2b(float f) {
    __bf16 h = (__bf16)f;
    return __builtin_bit_cast(ushort, h);
}
__device__ __forceinline__ __bf16 bhi(float x) { return (__bf16)x; }
__device__ __forceinline__ __bf16 blo(float x) {
    __bf16 h = (__bf16)x;
    return (__bf16)(x - (float)h);
}

// Dual-dtype loads: isb==1 -> bf16 (ushort), else fp32.
__device__ __forceinline__ float ldx(const void* p, long i, int isb) {
    return isb ? b2f(((const ushort*)p)[i]) : ((const float*)p)[i];
}
__device__ __forceinline__ f32x4 ldx4(const void* p, long i, int isb) {
    f32x4 r;
    if (isb) {
        uint2 v = *(const uint2*)((const ushort*)p + i);   // 8 B, aligned (i%4==0)
        r[0] = b2f((ushort)(v.x & 0xffff));
        r[1] = b2f((ushort)(v.x >> 16));
        r[2] = b2f((ushort)(v.y & 0xffff));
        r[3] = b2f((ushort)(v.y >> 16));
    } else {
        r = *(const f32x4*)((const float*)p + i);
    }
    return r;
}

__device__ __forceinline__ float frcp(float x) {
    return __builtin_amdgcn_rcpf(x);      // v_rcp_f32, ~1 ulp
}

__device__ __forceinline__ float mishf(float x) {
    // mish(x) = x * tanh(log1p(e^x)) = x * (1 - 2/((1+e^x)^2 + 1))
    float t = __expf(x);
    float u = 1.0f + t;
    float r = 1.0f - 2.0f * frcp(u * u + 1.0f);
    return x * r;
}

// ---------------------------------------------------------------------------
// Static graph geometry.
// Block order: hit_sp, oph_pmt, pmt_opf, sp_evt, opf_evt, evt_sp, sp_hit,
//              evt_opf, opf_pmt, pmt_oph
// ---------------------------------------------------------------------------
#define E0 300000
#define E1 400000
#define E2 60000
#define E3 50000
#define E4 2000
#define E5 50000
#define E6 300000
#define E7 2000
#define E8 60000
#define E9 400000
#define ETOT 1624000
// bucket shift (W = 1<<SH targets/bucket; W<=32 so LDS <= 16KB => 8 blk/CU)
#define SH0 5
#define SH1 4
#define SH2 0
#define SH3 0
#define SH4 0
#define SH5 5
#define SH6 5
#define SH7 0
#define SH8 4
#define SH9 5
// bucket counts: {1563,1875,2000,256,256,1563,9375,2000,1875,6250} sum 27013
#define GB0 0
#define GB1 1563
#define GB2 3438
#define GB3 5438
#define GB4 5694
#define GB5 5950
#define GB6 7513
#define GB7 16888
#define GB8 18888
#define GB9 20763
#define NB_TOTAL 27013
#define NB_PAD   27136

// ---------------------------------------------------------------------------
// Dtype probe: flag[0]=1 -> bf16 inputs, 0 -> fp32.
// ---------------------------------------------------------------------------
__global__ __launch_bounds__(256) void detect_kernel(const ushort* __restrict__ u,
                                                     int* __restrict__ flag)
{
    __shared__ int s_cnt;
    if (threadIdx.x == 0) s_cnt = 0;
    __syncthreads();
    int cnt = 0;
    for (int i = threadIdx.x; i < 8192; i += 256) {
        ushort v = u[2 * i];
        if ((v & 0x7F80u) == 0x7F80u) cnt++;
    }
#pragma unroll
    for (int off = 32; off; off >>= 1) cnt += __shfl_xor(cnt, off, 64);
    if ((threadIdx.x & 63) == 0) atomicAdd(&s_cnt, cnt);
    __syncthreads();
    if (threadIdx.x == 0) flag[0] = (s_cnt == 0) ? 1 : 0;
}

// ---------------------------------------------------------------------------
// Sort pass 1: count edges per bucket.
// ---------------------------------------------------------------------------
__global__ __launch_bounds__(256) void count_kernel(
    const int* __restrict__ e0, const int* __restrict__ e1,
    const int* __restrict__ e2, const int* __restrict__ e3,
    const int* __restrict__ e4, const int* __restrict__ e5,
    const int* __restrict__ e6, const int* __restrict__ e7,
    const int* __restrict__ e8, const int* __restrict__ e9,
    int* __restrict__ cnt)
{
    long gid = (long)blockIdx.x * 256 + threadIdx.x;
    long gstride = (long)gridDim.x * 256;
#define CSEG(EP, EN, GB, SHV) \
    for (long i = gid; i < (EN); i += gstride) { \
        int d = (EP)[(EN) + i]; \
        atomicAdd(&cnt[(GB) + (d >> (SHV))], 1); \
    }
    CSEG(e0, E0, GB0, SH0) CSEG(e1, E1, GB1, SH1) CSEG(e2, E2, GB2, SH2)
    CSEG(e3, E3, GB3, SH3) CSEG(e4, E4, GB4, SH4) CSEG(e5, E5, GB5, SH5)
    CSEG(e6, E6, GB6, SH6) CSEG(e7, E7, GB7, SH7) CSEG(e8, E8, GB8, SH8)
    CSEG(e9, E9, GB9, SH9)
#undef CSEG
}

// ---------------------------------------------------------------------------
// Sort pass 2: exclusive scan of NB_TOTAL bucket counts (single workgroup).
// ---------------------------------------------------------------------------
__global__ __launch_bounds__(256) void scan_kernel(const int* __restrict__ cnt,
                                                   int* __restrict__ off)
{
    __shared__ int wsum[4];
    int tid = threadIdx.x;
    const int STRIP = (NB_TOTAL + 255) / 256;     // 106
    int s0 = tid * STRIP;
    int s1 = s0 + STRIP; if (s1 > NB_TOTAL) s1 = NB_TOTAL;
    if (s0 > NB_TOTAL) s0 = NB_TOTAL;
    int sum = 0;
    for (int i = s0; i < s1; ++i) sum += cnt[i];
    int lane = tid & 63, wid = tid >> 6;
    int incl = sum;
#pragma unroll
    for (int o = 1; o < 64; o <<= 1) {
        int v = __shfl_up(incl, o, 64);
        if (lane >= o) incl += v;
    }
    if (lane == 63) wsum[wid] = incl;
    __syncthreads();
    int wbase = 0;
    for (int wq = 0; wq < wid; ++wq) wbase += wsum[wq];
    int run = wbase + incl - sum;                 // exclusive prefix of strip
    for (int i = s0; i < s1; ++i) { off[i] = run; run += cnt[i]; }
}

// ---------------------------------------------------------------------------
// Sort pass 3: scatter (s,d) into bucket-contiguous order.
// After this, off[b] == end of bucket b (start = off[b-1] or 0).
// ---------------------------------------------------------------------------
__global__ __launch_bounds__(256) void scatter_kernel(
    const int* __restrict__ e0, const int* __restrict__ e1,
    const int* __restrict__ e2, const int* __restrict__ e3,
    const int* __restrict__ e4, const int* __restrict__ e5,
    const int* __restrict__ e6, const int* __restrict__ e7,
    const int* __restrict__ e8, const int* __restrict__ e9,
    int* __restrict__ off, int2* __restrict__ sdv)
{
    long gid = (long)blockIdx.x * 256 + threadIdx.x;
    long gstride = (long)gridDim.x * 256;
#define SSEG(EP, EN, GB, SHV) \
    for (long i = gid; i < (EN); i += gstride) { \
        int s = (EP)[i], d = (EP)[(EN) + i]; \
        int pos = atomicAdd(&off[(GB) + (d >> (SHV))], 1); \
        sdv[pos] = make_int2(s, d); \
    }
    SSEG(e0, E0, GB0, SH0) SSEG(e1, E1, GB1, SH1) SSEG(e2, E2, GB2, SH2)
    SSEG(e3, E3, GB3, SH3) SSEG(e4, E4, GB4, SH4) SSEG(e5, E5, GB5, SH5)
    SSEG(e6, E6, GB6, SH6) SSEG(e7, E7, GB7, SH7) SSEG(e8, E8, GB8, SH8)
    SSEG(e9, E9, GB9, SH9)
#undef SSEG
}

// ---------------------------------------------------------------------------
// Bucketed edge pass, 4 edges per wave:
//   lane layout: g = lane>>4 (edge slot), fl = (lane&15)*4 (feature base).
//   One dwordx4 gather instruction covers 4 edges' 256B rows.
//   Reduce: 4 shfl_xor levels within 16-lane groups.
//   LDS accumulation, plain coalesced global stores, no global f32 atomics.
// ---------------------------------------------------------------------------
template <int SHIFT>
__global__ __launch_bounds__(256, 8) void edge_bucket_kernel(
    const void* xsrc, long sOff, int smode,
    const void* xtgt, long tOff, int tmode,
    const int2* __restrict__ sdv, const int* __restrict__ boff,
    int gb0, int lo, int hi,
    const void* ew, long ewOff, const void* eb, long ebOff,
    float* __restrict__ den, float* __restrict__ num,
    const int* __restrict__ flagp)
{
    constexpr int W = 1 << SHIFT;
    __shared__ float acc[W * 128];                // [row][den(64)|num(64)]

    int isb = flagp[0];
    int sm = (smode == 2) ? isb : smode;
    int tm = (tmode == 2) ? isb : tmode;

    int tid = threadIdx.x, lane = tid & 63, wid = tid >> 6;
    int g = lane >> 4;                 // edge slot 0..3 within wave
    int fl = (lane & 15) * 4;          // feature base (float4)
    int t0 = lo + blockIdx.x * W;
    int rows = hi - t0; if (rows > W) rows = W;
    int gb = gb0 + blockIdx.x;
    int start = (gb == 0) ? 0 : boff[gb - 1];
    int end = boff[gb];

    for (int i = tid; i < rows * 128; i += 256) acc[i] = 0.0f;
    __syncthreads();

    f32x4 wI4 = ldx4(ew, ewOff + fl, isb);        // multiplies x_i (target)
    f32x4 wJ4 = ldx4(ew, ewOff + 64 + fl, isb);   // multiplies x_j (source)
    float bias = ldx(eb, ebOff, isb);

    // Wave processes quads of edges: base ib, slots ib+g; stride 16 (4 waves).
    int ib = start + wid * 4;
    int2 ec = make_int2(0, t0);
    f32x4 xjc = {}, xic = {};
    bool actc = false;
    if (ib < end) {
        int i = ib + g;
        actc = i < end;
        int ii = actc ? i : end - 1;
        ec = sdv[ii];
        xjc = ldx4(xsrc, sOff + (long)ec.x * 64 + fl, sm);
        xic = ldx4(xtgt, tOff + (long)ec.y * 64 + fl, tm);
    }
    while (ib < end) {
        int ibn = ib + 16;
        int2 en = make_int2(0, t0);
        f32x4 xjn = {}, xin = {};
        bool actn = false;
        if (ibn < end) {
            int i = ibn + g;
            actn = i < end;
            int ii = actn ? i : end - 1;
            en = sdv[ii];
            xjn = ldx4(xsrc, sOff + (long)en.x * 64 + fl, sm);
            xin = ldx4(xtgt, tOff + (long)en.y * 64 + fl, tm);
        }
        // Process current quad: per-lane partial dot (4 features), then
        // reduce across the 16 lanes of this edge's group.
        float part = xic[0] * wI4[0] + xic[1] * wI4[1]
                   + xic[2] * wI4[2] + xic[3] * wI4[3]
                   + xjc[0] * wJ4[0] + xjc[1] * wJ4[1]
                   + xjc[2] * wJ4[2] + xjc[3] * wJ4[3];
#pragma unroll
        for (int o = 8; o; o >>= 1) part += __shfl_xor(part, o, 64);
        float t = part + bias;
        float w = frcp(1.0f + __expf(-t));        // sigmoid
        if (actc) {
            int r = ec.y - t0;
            float* rowp = &acc[r * 128];
#pragma unroll
            for (int j = 0; j < 4; ++j) {
                float m = w * xjc[j];
                float ex = __expf(m);
                atomicAdd(&rowp[fl + j], ex);
                atomicAdd(&rowp[64 + fl + j], ex * m);
            }
        }
        ib = ibn; ec = en; xjc = xjn; xic = xin; actc = actn;
    }
    __syncthreads();

    for (int i2 = tid; i2 < rows * 16; i2 += 256) {
        int r = i2 >> 4, c = (i2 & 15) * 4;
        long go = (long)(t0 - lo + r) * 64 + c;
        *(f32x4*)&den[go] = *(const f32x4*)&acc[r * 128 + c];
        *(f32x4*)&num[go] = *(const f32x4*)&acc[r * 128 + 64 + c];
    }
}

// ---------------------------------------------------------------------------
// Fallback edge pass (global atomics) for small-workspace cases.
// ---------------------------------------------------------------------------
__global__ __launch_bounds__(256) void edge_kernel(
    const void* xsrc, long sOff, int smode,
    const void* xtgt, long tOff, int tmode,
    const int* __restrict__ eidx, int E,
    const void* ew, long ewOff, const void* eb, long ebOff,
    float* __restrict__ den, float* __restrict__ num,
    int lo, int hi, const int* __restrict__ flagp)
{
    int isb = flagp[0];
    int sm = (smode == 2) ? isb : smode;
    int tm = (tmode == 2) ? isb : tmode;

    int lane = threadIdx.x & 63;
    float wI = ldx(ew, ewOff + lane, isb);
    float wJ = ldx(ew, ewOff + 64 + lane, isb);
    float bias = ldx(eb, ebOff, isb);

    int nwaves = gridDim.x * 4;
    for (int e = blockIdx.x * 4 + (threadIdx.x >> 6); e < E; e += nwaves) {
        int d = eidx[E + e];
        if (d < lo || d >= hi) continue;
        int s = eidx[e];
        float xj = ldx(xsrc, sOff + (long)s * 64 + lane, sm);
        float xi = ldx(xtgt, tOff + (long)d * 64 + lane, tm);
        float part = xi * wI + xj * wJ;
#pragma unroll
        for (int off = 32; off; off >>= 1) part += __shfl_xor(part, off, 64);
        float t = part + bias;
        float w = frcp(1.0f + __expf(-t));
        float m = w * xj;
        float ex = __expf(m);
        long idx = (long)(d - lo) * 64 + lane;
        unsafeAtomicAdd(&den[idx], ex);
        unsafeAtomicAdd(&num[idx], ex * m);
    }
}

// ---------------------------------------------------------------------------
// MLP pass: aggr=num*rcp(den); 2-layer mish MLP via MFMA 16x16x32 bf16,
// hi/lo-split A for ~fp32 accuracy.
// ---------------------------------------------------------------------------
__global__ __launch_bounds__(256) void mlp_kernel(
    const float* __restrict__ den, const float* __restrict__ num,
    const void* xt, long xtOff, int tmode,
    const void* w1, long w1Off, const void* b1, long b1Off,
    const void* w2, long w2Off, const void* b2, long b2Off,
    float* outf, void* outd, long outOff,
    int lo, int hi, int accumulate, const int* __restrict__ flagp)
{
    __shared__ __align__(16) ushort W1t[64][144];
    __shared__ __align__(16) ushort W2t[64][80];
    __shared__ __align__(16) float  A2s[4][16][68];

    int isb = flagp[0];
    int tm = (tmode == 2) ? isb : tmode;
    ushort* ob16 = nullptr;
    float*  ob32 = nullptr;
    if (outd) {
        if (isb) ob16 = (ushort*)outd + outOff;
        else     ob32 = (float*)outd + outOff;
    }

    for (int idx = threadIdx.x; idx < 128 * 64; idx += 256) {
        int k = idx >> 6, n = idx & 63;
        W1t[n][k] = f2b(ldx(w1, w1Off + idx, isb));
    }
    for (int idx = threadIdx.x; idx < 64 * 64; idx += 256) {
        int k = idx >> 6, n = idx & 63;
        W2t[n][k] = f2b(ldx(w2, w2Off + idx, isb));
    }
    __syncthreads();

    int wid = threadIdx.x >> 6, lane = threadIdx.x & 63;
    int m16 = lane & 15, quad = lane >> 4;
    int ntiles = (hi - lo + 15) >> 4;

    for (int tile = blockIdx.x * 4 + wid; tile < ntiles; tile += gridDim.x * 4) {
        int base = lo + (tile << 4);
        int nodeA = base + m16;
        if (nodeA > hi - 1) nodeA = hi - 1;
        long aggoff = (long)(nodeA - lo) * 64;
        long xoff   = (long)nodeA * 64;

        bf16x8 Ahi[4], Alo[4];
#pragma unroll
        for (int s2 = 0; s2 < 2; ++s2) {
            int k0 = s2 * 32 + quad * 8;
            f32x4 n0v = *(const f32x4*)(num + aggoff + k0);
            f32x4 n1v = *(const f32x4*)(num + aggoff + k0 + 4);
            f32x4 d0v = *(const f32x4*)(den + aggoff + k0);
            f32x4 d1v = *(const f32x4*)(den + aggoff + k0 + 4);
#pragma unroll
            for (int j = 0; j < 4; ++j) {
                float a0 = n0v[j] * frcp(d0v[j] + 1e-16f);
                float a1 = n1v[j] * frcp(d1v[j] + 1e-16f);
                Ahi[s2][j]     = bhi(a0);
                Alo[s2][j]     = blo(a0);
                Ahi[s2][j + 4] = bhi(a1);
                Alo[s2][j + 4] = blo(a1);
            }
        }
#pragma unroll
        for (int s2 = 2; s2 < 4; ++s2) {
            int k0 = (s2 - 2) * 32 + quad * 8;
            f32x4 x0 = ldx4(xt, xtOff + xoff + k0, tm);
            f32x4 x1 = ldx4(xt, xtOff + xoff + k0 + 4, tm);
#pragma unroll
            for (int j = 0; j < 4; ++j) {
                Ahi[s2][j]     = bhi(x0[j]);
                Alo[s2][j]     = blo(x0[j]);
                Ahi[s2][j + 4] = bhi(x1[j]);
                Alo[s2][j + 4] = blo(x1[j]);
            }
        }

        f32x4 acc[4] = {};
#pragma unroll
        for (int t = 0; t < 4; ++t) {
#pragma unroll
            for (int s = 0; s < 4; ++s) {
                bf16x8 B = __builtin_bit_cast(bf16x8,
                    *(const int4*)&W1t[t * 16 + m16][s * 32 + quad * 8]);
                acc[t] = __builtin_amdgcn_mfma_f32_16x16x32_bf16(Ahi[s], B, acc[t], 0, 0, 0);
                acc[t] = __builtin_amdgcn_mfma_f32_16x16x32_bf16(Alo[s], B, acc[t], 0, 0, 0);
            }
        }
#pragma unroll
        for (int t = 0; t < 4; ++t) {
            float bias = ldx(b1, b1Off + t * 16 + m16, isb);
#pragma unroll
            for (int r = 0; r < 4; ++r) {
                float x = acc[t][r] + bias;
                A2s[wid][quad * 4 + r][t * 16 + m16] = mishf(x);
            }
        }
        asm volatile("s_waitcnt lgkmcnt(0)" ::: "memory");

        bf16x8 A2hi[2], A2lo[2];
#pragma unroll
        for (int s2 = 0; s2 < 2; ++s2) {
            int k0 = s2 * 32 + quad * 8;
            f32x4 h0 = *(const f32x4*)&A2s[wid][m16][k0];
            f32x4 h1 = *(const f32x4*)&A2s[wid][m16][k0 + 4];
#pragma unroll
            for (int j = 0; j < 4; ++j) {
                A2hi[s2][j]     = bhi(h0[j]);
                A2lo[s2][j]     = blo(h0[j]);
                A2hi[s2][j + 4] = bhi(h1[j]);
                A2lo[s2][j + 4] = blo(h1[j]);
            }
        }
        f32x4 acc2[4] = {};
#pragma unroll
        for (int t = 0; t < 4; ++t) {
#pragma unroll
            for (int s = 0; s < 2; ++s) {
                bf16x8 B = __builtin_bit_cast(bf16x8,
                    *(const int4*)&W2t[t * 16 + m16][s * 32 + quad * 8]);
                acc2[t] = __builtin_amdgcn_mfma_f32_16x16x32_bf16(A2hi[s], B, acc2[t], 0, 0, 0);
                acc2[t] = __builtin_amdgcn_mfma_f32_16x16x32_bf16(A2lo[s], B, acc2[t], 0, 0, 0);
            }
        }
#pragma unroll
        for (int t = 0; t < 4; ++t) {
            float bias = ldx(b2, b2Off + t * 16 + m16, isb);
#pragma unroll
            for (int r = 0; r < 4; ++r) {
                int node = base + quad * 4 + r;
                if (node < hi) {
                    long idx = (long)node * 64 + t * 16 + m16;
                    float y = mishf(acc2[t][r] + bias);
                    if (accumulate)
                        y += outf ? outf[idx] : (ob16 ? b2f(ob16[idx]) : ob32[idx]);
                    if (outf) outf[idx] = y;
                    if (ob16) ob16[idx] = f2b(y);
                    else if (ob32) ob32[idx] = y;
                }
            }
        }
    }
}

// ---------------------------------------------------------------------------
struct HBuf { const void* base; long off; int mode; };   // 0 f32, 1 bf16, 2 flag

// Sorted path: bucketed edge pass + mlp. No memsets needed.
template <int SHIFT>
static void run_block_sorted(HBuf src, HBuf tgt, int n_tgt, int bi, int gbase,
                             const int2* sdv, const int* boff,
                             const void* edge_w, const void* edge_b,
                             const void* w1, const void* b1,
                             const void* w2, const void* b2,
                             float* den, float* num, int chunkCap,
                             float* outf, void* outd, long outOff, int accumulate,
                             const int* flagp, hipStream_t stream)
{
    constexpr int W = 1 << SHIFT;
    for (int lo = 0; lo < n_tgt; lo += chunkCap) {
        int hi = lo + chunkCap < n_tgt ? lo + chunkCap : n_tgt;
        int nb = (hi - lo + W - 1) >> SHIFT;
        edge_bucket_kernel<SHIFT><<<nb, 256, 0, stream>>>(
            src.base, src.off, src.mode, tgt.base, tgt.off, tgt.mode,
            sdv, boff, gbase + (lo >> SHIFT), lo, hi,
            edge_w, (long)bi * 128, edge_b, (long)bi,
            den, num, flagp);
        int ntiles = (hi - lo + 15) / 16;
        int mblocks = (ntiles + 3) / 4;
        if (mblocks > 2048) mblocks = 2048;
        mlp_kernel<<<mblocks, 256, 0, stream>>>(
            den, num, tgt.base, tgt.off, tgt.mode,
            w1, (long)bi * 128 * 64, b1, (long)bi * 64,
            w2, (long)bi * 64 * 64, b2, (long)bi * 64,
            outf, outd, outOff, lo, hi, accumulate, flagp);
    }
}

// Fallback path (global atomics).
static void run_block(HBuf src, HBuf tgt, const int* e, int E, int n_tgt, int bi,
                      const void* edge_w, const void* edge_b,
                      const void* w1, const void* b1,
                      const void* w2, const void* b2,
                      float* den, float* num, int chunkCap,
                      float* outf, void* outd, long outOff, int accumulate,
                      const int* flagp, hipStream_t stream)
{
    for (int lo = 0; lo < n_tgt; lo += chunkCap) {
        int hi = lo + chunkCap < n_tgt ? lo + chunkCap : n_tgt;
        size_t bytes = (size_t)(hi - lo) * 64 * 4;
        if (hi - lo == chunkCap) {
            (void)hipMemsetAsync(den, 0, 2 * bytes, stream);
        } else {
            (void)hipMemsetAsync(den, 0, bytes, stream);
            (void)hipMemsetAsync(num, 0, bytes, stream);
        }
        int eblocks = (E + 3) / 4;
        if (eblocks > 2048) eblocks = 2048;
        edge_kernel<<<eblocks, 256, 0, stream>>>(
            src.base, src.off, src.mode, tgt.base, tgt.off, tgt.mode,
            e, E, edge_w, (long)bi * 128, edge_b, (long)bi,
            den, num, lo, hi, flagp);
        int ntiles = (hi - lo + 15) / 16;
        int mblocks = (ntiles + 3) / 4;
        if (mblocks > 2048) mblocks = 2048;
        mlp_kernel<<<mblocks, 256, 0, stream>>>(
            den, num, tgt.base, tgt.off, tgt.mode,
            w1, (long)bi * 128 * 64, b1, (long)bi * 64,
            w2, (long)bi * 64 * 64, b2, (long)bi * 64,
            outf, outd, outOff, lo, hi, accumulate, flagp);
    }
}

extern "C" void kernel_launch(void* const* d_in, const int* in_sizes, int n_in,
                              void* d_out, int out_size, void* d_ws, size_t ws_size,
                              hipStream_t stream)
{
    (void)in_sizes; (void)n_in; (void)out_size;

    const void* x_hit = d_in[0];
    const void* x_sp  = d_in[1];
    const void* x_oph = d_in[2];
    const void* x_pmt = d_in[3];
    const void* x_opf = d_in[4];
    const void* x_evt = d_in[5];
    const void* edge_w = d_in[6];
    const void* edge_b = d_in[7];
    const void* w1 = d_in[8];
    const void* b1 = d_in[9];
    const void* w2 = d_in[10];
    const void* b2 = d_in[11];
    const int* e_hit_sp  = (const int*)d_in[12];
    const int* e_oph_pmt = (const int*)d_in[13];
    const int* e_pmt_opf = (const int*)d_in[14];
    const int* e_sp_evt  = (const int*)d_in[15];
    const int* e_opf_evt = (const int*)d_in[16];
    const int* e_evt_sp  = (const int*)d_in[17];
    const int* e_sp_hit  = (const int*)d_in[18];
    const int* e_evt_opf = (const int*)d_in[19];
    const int* e_opf_pmt = (const int*)d_in[20];
    const int* e_pmt_oph = (const int*)d_in[21];

    const long off_p = 0, off_n = 19200000, off_oph = 22400000,
               off_pmt = 35200000, off_opf = 37120000, off_i = 37248000;

    char* wsc = (char*)d_ws;
    int* flagp = (int*)(wsc + ((ws_size - 64) & ~(size_t)15));
    size_t usable = ws_size > 256 ? ws_size - 256 : 0;
    float* wsf = (float*)d_ws;

    detect_kernel<<<1, 256, 0, stream>>>((const ushort*)x_hit, flagp);

    const size_t nodeFloats = 3200000ull * 2 + 1920000ull * 2 + 128000ull * 2 + 16384ull;
    const size_t nodeBytes  = nodeFloats * 4;
    const size_t sortFloats = (size_t)ETOT * 2 + 2 * NB_PAD;
    const size_t sortBytes  = sortFloats * 4;

    bool sortedPath = usable >= nodeBytes + sortBytes + (4ull << 20);
    bool fp32path   = usable >= nodeBytes + (8ull << 20);

    HBuf bhit{x_hit, 0, 2}, bsp{x_sp, 0, 2}, boph{x_oph, 0, 2},
         bpmt{x_pmt, 0, 2}, bopf{x_opf, 0, 2}, bevt{x_evt, 0, 2};

    if (sortedPath) {
        float* n0   = wsf;
        float* n1   = n0 + 3200000;
        float* pmt0 = n1 + 3200000;
        float* pmt1 = pmt0 + 1920000;
        float* opf0 = pmt1 + 1920000;
        float* opf1 = opf0 + 128000;
        float* iA   = opf1 + 128000;
        int2* sdv   = (int2*)(wsf + nodeFloats);
        int* cnt    = (int*)(sdv + ETOT);
        int* boff   = cnt + NB_PAD;
        float* den  = (float*)(boff + NB_PAD);

        size_t capBytes = usable - nodeBytes - sortBytes;
        long cap = (long)(capBytes / 512);
        if (cap > 300000) cap = 300000;
        cap &= ~63L;
        if (cap < 64) cap = 64;
        int chunkCap = (int)cap;
        float* num = den + (size_t)chunkCap * 64;

        // Build bucket-sorted edge lists (geometry all static).
        (void)hipMemsetAsync(cnt, 0, NB_PAD * sizeof(int), stream);
        count_kernel<<<512, 256, 0, stream>>>(
            e_hit_sp, e_oph_pmt, e_pmt_opf, e_sp_evt, e_opf_evt,
            e_evt_sp, e_sp_hit, e_evt_opf, e_opf_pmt, e_pmt_oph, cnt);
        scan_kernel<<<1, 256, 0, stream>>>(cnt, boff);
        scatter_kernel<<<512, 256, 0, stream>>>(
            e_hit_sp, e_oph_pmt, e_pmt_opf, e_sp_evt, e_opf_evt,
            e_evt_sp, e_sp_hit, e_evt_opf, e_opf_pmt, e_pmt_oph, boff, sdv);

        HBuf bn0{n0, 0, 0}, bn1{n1, 0, 0}, bpmt0{pmt0, 0, 0}, bpmt1{pmt1, 0, 0},
             bopf0{opf0, 0, 0}, bopf1{opf1, 0, 0}, biA{iA, 0, 0};

#define WS edge_w, edge_b, w1, b1, w2, b2, den, num, chunkCap
        run_block_sorted<SH0>(bhit,  bsp,    50000, 0, GB0, sdv, boff, WS, n0,   nullptr, 0,      0, flagp, stream);
        run_block_sorted<SH1>(boph,  bpmt,   30000, 1, GB1, sdv, boff, WS, pmt0, nullptr, 0,      0, flagp, stream);
        run_block_sorted<SH2>(bpmt0, bopf,    2000, 2, GB2, sdv, boff, WS, opf0, nullptr, 0,      0, flagp, stream);
        run_block_sorted<SH3>(bn0,   bevt,     256, 3, GB3, sdv, boff, WS, iA,   d_out, off_i,    0, flagp, stream);
        run_block_sorted<SH4>(bopf0, bevt,     256, 4, GB4, sdv, boff, WS, iA,   d_out, off_i,    1, flagp, stream);
        run_block_sorted<SH5>(biA,   bn0,    50000, 5, GB5, sdv, boff, WS, n1,   d_out, off_n,    0, flagp, stream);
        run_block_sorted<SH6>(bn1,   bhit,  300000, 6, GB6, sdv, boff, WS, nullptr, d_out, off_p, 0, flagp, stream);
        run_block_sorted<SH7>(biA,   bopf0,   2000, 7, GB7, sdv, boff, WS, opf1, d_out, off_opf,  0, flagp, stream);
        run_block_sorted<SH8>(bopf1, bpmt0,  30000, 8, GB8, sdv, boff, WS, pmt1, d_out, off_pmt,  0, flagp, stream);
        run_block_sorted<SH9>(bpmt1, boph,  200000, 9, GB9, sdv, boff, WS, nullptr, d_out, off_oph, 0, flagp, stream);
#undef WS
    } else if (fp32path) {
        size_t capBytes = usable - nodeBytes;
        long cap = (long)(capBytes / 512);
        if (cap > 300000) cap = 300000;
        cap &= ~15L;
        if (cap < 16) cap = 16;
        int chunkCap = (int)cap;
        float* den = wsf + nodeFloats;
        float* num = den + (size_t)chunkCap * 64;

        float* n0   = wsf;
        float* n1   = n0 + 3200000;
        float* pmt0 = n1 + 3200000;
        float* pmt1 = pmt0 + 1920000;
        float* opf0 = pmt1 + 1920000;
        float* opf1 = opf0 + 128000;
        float* iA   = opf1 + 128000;
        HBuf bn0{n0, 0, 0}, bn1{n1, 0, 0}, bpmt0{pmt0, 0, 0}, bpmt1{pmt1, 0, 0},
             bopf0{opf0, 0, 0}, bopf1{opf1, 0, 0}, biA{iA, 0, 0};

#define W edge_w, edge_b, w1, b1, w2, b2, den, num, chunkCap
        run_block(bhit,  bsp,   e_hit_sp,  300000,  50000, 0, W, n0,   nullptr, 0,      0, flagp, stream);
        run_block(boph,  bpmt,  e_oph_pmt, 400000,  30000, 1, W, pmt0, nullptr, 0,      0, flagp, stream);
        run_block(bpmt0, bopf,  e_pmt_opf,  60000,   2000, 2, W, opf0, nullptr, 0,      0, flagp, stream);
        run_block(bn0,   bevt,  e_sp_evt,   50000,    256, 3, W, iA,   d_out, off_i,    0, flagp, stream);
        run_block(bopf0, bevt,  e_opf_evt,   2000,    256, 4, W, iA,   d_out, off_i,    1, flagp, stream);
        run_block(biA,   bn0,   e_evt_sp,   50000,  50000, 5, W, n1,   d_out, off_n,    0, flagp, stream);
        run_block(bn1,   bhit,  e_sp_hit,  300000, 300000, 6, W, nullptr, d_out, off_p, 0, flagp, stream);
        run_block(biA,   bopf0, e_evt_opf,   2000,   2000, 7, W, opf1, d_out, off_opf,  0, flagp, stream);
        run_block(bopf1, bpmt0, e_opf_pmt,  60000,  30000, 8, W, pmt1, d_out, off_pmt,  0, flagp, stream);
        run_block(bpmt1, boph,  e_pmt_oph, 400000, 200000, 9, W, nullptr, d_out, off_oph, 0, flagp, stream);
#undef W
    } else {
        long cap = (long)(usable / 512);
        if (cap > 300000) cap = 300000;
        cap &= ~15L;
        if (cap < 16) cap = 16;
        int chunkCap = (int)cap;
        float* den = wsf;
        float* num = den + (size_t)chunkCap * 64;

        HBuf dn{d_out, off_n, 2}, dpmt{d_out, off_pmt, 2}, dopf{d_out, off_opf, 2},
             di{d_out, off_i, 2};
#define W edge_w, edge_b, w1, b1, w2, b2, den, num, chunkCap
        run_block(bhit, bsp,  e_hit_sp,  300000,  50000, 0, W, nullptr, d_out, off_n,   0, flagp, stream);
        run_block(boph, bpmt, e_oph_pmt, 400000,  30000, 1, W, nullptr, d_out, off_pmt, 0, flagp, stream);
        run_block(dpmt, bopf, e_pmt_opf,  60000,   2000, 2, W, nullptr, d_out, off_opf, 0, flagp, stream);
        run_block(dn,   bevt, e_sp_evt,   50000,    256, 3, W, nullptr, d_out, off_i,   0, flagp, stream);
        run_block(dopf, bevt, e_opf_evt,   2000,    256, 4, W, nullptr, d_out, off_i,   1, flagp, stream);
        run_block(di,   dn,   e_evt_sp,   50000,  50000, 5, W, nullptr, d_out, off_n,   0, flagp, stream);
        run_block(dn,   bhit, e_sp_hit,  300000, 300000, 6, W, nullptr, d_out, off_p,   0, flagp, stream);
        run_block(di,   dopf, e_evt_opf,   2000,   2000, 7, W, nullptr, d_out, off_opf, 0, flagp, stream);
        run_block(dopf, dpmt, e_opf_pmt,  60000,  30000, 8, W, nullptr, d_out, off_pmt, 0, flagp, stream);
        run_block(dpmt, boph, e_pmt_oph, 400000, 200000, 9, W, nullptr, d_out, off_oph, 0, flagp, stream);
#undef W
    }
}